// Round 1
// baseline (1348.684 us; speedup 1.0000x reference)
//
#include <hip/hip_runtime.h>
#include <stdint.h>

#define NN 50000
#define DD 80
#define NE 800000
#define EDIM 16
#define PED 37
#define NG 256
#define NLAY 4
#define KZ 480
#define NOUT 240
#define MPAD 50048
#define AVG_LD 1.4059212841460147f
#define S5 0.0031622776601683794f

typedef __bf16 bf16x8 __attribute__((ext_vector_type(8)));
typedef float f32x4 __attribute__((ext_vector_type(4)));

__device__ __forceinline__ unsigned short f2bf(float f){
  union { float f; unsigned u; } v; v.f = f;
  return (unsigned short)((v.u + 0x7fffu + ((v.u >> 16) & 1u)) >> 16);
}

// ---------------- setup ----------------
__global__ void k_setup(int* deg, unsigned short* Z){
  int idx = blockIdx.x*blockDim.x + threadIdx.x;
  if(idx < NN) deg[idx] = 0;
  int t = idx - NN;
  if(t >= 0 && t < (MPAD-NN)*KZ) Z[(size_t)NN*KZ + t] = 0;
}

__global__ void k_hist(const int* __restrict__ tgt, int* deg){
  int e = blockIdx.x*blockDim.x + threadIdx.x;
  if(e < NE) atomicAdd(&deg[tgt[e]], 1);
}

__global__ void k_scan(const int* __restrict__ deg, int* off, int* pos){
  __shared__ int sums[1024];
  int t = threadIdx.x;
  const int CH = (NN + 1023)/1024;
  int start = t*CH, end = min(start+CH, NN);
  int s = 0;
  for(int i=start;i<end;++i) s += deg[i];
  sums[t] = s; __syncthreads();
  for(int d=1; d<1024; d<<=1){
    int v = (t>=d) ? sums[t-d] : 0;
    __syncthreads();
    sums[t] += v;
    __syncthreads();
  }
  int base = (t==0) ? 0 : sums[t-1];
  int run = base;
  for(int i=start;i<end;++i){ off[i]=run; pos[i]=run; run += deg[i]; }
  if(t==1023) off[NN] = sums[1023];
}

__global__ void k_fill(const int* __restrict__ ei, int* pos, int* esrc, int* eid){
  int e = blockIdx.x*blockDim.x + threadIdx.x;
  if(e < NE){
    int t = ei[NE + e];
    int idx = atomicAdd(&pos[t], 1);
    esrc[idx] = ei[e];
    eid[idx] = e;
  }
}

__global__ void k_gather(const float* __restrict__ ea, const int* __restrict__ eid,
                         float* __restrict__ ea_s){
  int j = blockIdx.x*blockDim.x + threadIdx.x;
  if(j < NE){
    int e = eid[j];
    const float4* s = (const float4*)(ea + (size_t)e*EDIM);
    float4* d = (float4*)(ea_s + (size_t)j*EDIM);
    d[0]=s[0]; d[1]=s[1]; d[2]=s[2]; d[3]=s[3];
  }
}

// ---------------- per-layer ----------------
__global__ void k_xp(const float* __restrict__ xc, const float* __restrict__ PE,
                     const float* __restrict__ pw, const float* __restrict__ pb,
                     float* __restrict__ xp){
  int idx = blockIdx.x*blockDim.x + threadIdx.x;
  if(idx >= NN*DD) return;
  int i = idx / DD, c = idx % DD;
  float s = xc[idx] + pb[c];
  const float* per = PE + (size_t)i*PED;
  for(int p=0;p<PED;++p) s += per[p]*pw[p*DD + c];
  xp[idx] = s;
}

__global__ __launch_bounds__(256) void k_agg(
    const float* __restrict__ xp, const float* __restrict__ ea_s,
    const int* __restrict__ off, const int* __restrict__ esrc,
    unsigned short* __restrict__ Z, float2* __restrict__ sc){
  int g = blockIdx.x*8 + (threadIdx.x>>5);
  int t = threadIdx.x & 31;
  if(g >= NN) return;
  int lo = off[g], hi = off[g+1];
  int d = hi - lo;
  float s0=0,s1=0,s2=0,q0=0,q1=0,q2=0;
  float INF = __builtin_huge_valf();
  float mn0=INF,mn1=INF,mn2=INF,mx0=-INF,mx1=-INF,mx2=-INF;
  for(int j=lo;j<hi;++j){
    int sr = esrc[j];
    const float* xr = xp + (size_t)sr*DD;
    float v0 = xr[t];
    float v1 = xr[t+32];
    float v2 = (t<16) ? xr[64+t] : ea_s[(size_t)j*EDIM + (t-16)];
    s0+=v0; q0+=v0*v0; mn0=fminf(mn0,v0); mx0=fmaxf(mx0,v0);
    s1+=v1; q1+=v1*v1; mn1=fminf(mn1,v1); mx1=fmaxf(mx1,v1);
    s2+=v2; q2+=v2*v2; mn2=fminf(mn2,v2); mx2=fmaxf(mx2,v2);
  }
  float dc = (float)(d>0?d:1);
  float inv = 1.0f/dc;
  float m0=s0*inv, m1=s1*inv, m2=s2*inv;
  float sd0 = sqrtf(fmaxf(q0*inv - m0*m0, 0.0f) + 1e-5f);
  float sd1 = sqrtf(fmaxf(q1*inv - m1*m1, 0.0f) + 1e-5f);
  float sd2 = sqrtf(fmaxf(q2*inv - m2*m2, 0.0f) + 1e-5f);
  if(d==0){ mn0=mn1=mn2=0.0f; mx0=mx1=mx2=0.0f; }
  unsigned short* zr = Z + (size_t)g*KZ;
  zr[t]      = f2bf(m0);  zr[t+32]     = f2bf(m1);  zr[t+64]     = f2bf(m2);
  zr[96+t]   = f2bf(mn0); zr[96+t+32]  = f2bf(mn1); zr[96+t+64]  = f2bf(mn2);
  zr[192+t]  = f2bf(mx0); zr[192+t+32] = f2bf(mx1); zr[192+t+64] = f2bf(mx2);
  zr[288+t]  = f2bf(sd0); zr[288+t+32] = f2bf(sd1); zr[288+t+64] = f2bf(sd2);
  const float* xr = xp + (size_t)g*DD;
  float keep = (d>0) ? 1.0f : 0.0f;
  zr[384+t] = f2bf(keep*xr[t]);
  zr[416+t] = f2bf(keep*xr[32+t]);
  if(t<16) zr[448+t] = f2bf(keep*xr[64+t]);
  if(t==0) zr[464] = f2bf(1.0f);
  if(t>=1 && t<16) zr[464+t] = 0;
  if(t==16){
    float logd = logf(dc + 1.0f);
    sc[g] = make_float2(logd/AVG_LD, AVG_LD/logd);
  }
}

// build WcT [NOUT][KZ] bf16 from conv_w (layer slice), zero BN stat accumulators
__global__ void k_wprep(const float* __restrict__ cw, unsigned short* __restrict__ WcT,
                        float* stats){
  int idx = blockIdx.x*blockDim.x + threadIdx.x;
  if(idx < 160) stats[idx] = 0.0f;
  if(idx >= NOUT*KZ) return;
  int j = idx / KZ;          // output col 0..239
  int r = idx % KZ;          // Z dim
  int ks = j / DD, c = j % DD;
  float val = 0.0f;
  if(r < 384){
    int stat = r/96, m = r%96;                       // mean,mn,mx,std over src+ea
    val = cw[(size_t)(ks*704 + stat*176 + 80 + m)*DD + c];
  } else if(r < 464){
    int m = r - 384;                                 // xp combined (mean+mn+mx tgt rows)
    int b = ks*704 + m;
    val = cw[(size_t)b*DD + c] + cw[(size_t)(b+176)*DD + c] + cw[(size_t)(b+352)*DD + c];
  } else if(r == 464){
    float s = 0.0f; int b = ks*704 + 528;            // std tgt rows * sqrt(1e-5)
    for(int m=0;m<80;++m) s += cw[(size_t)(b+m)*DD + c];
    val = S5 * s;
  }
  WcT[idx] = f2bf(val);
}

__global__ __launch_bounds__(256) void k_gemm(
    const unsigned short* __restrict__ Z, const unsigned short* __restrict__ WcT,
    const float2* __restrict__ sc, const float* __restrict__ bias,
    float* __restrict__ outb){
  __shared__ __align__(16) unsigned short Zt[64*40];
  __shared__ __align__(16) unsigned short Wt[240*40];
  int tid = threadIdx.x;
  int wave = tid >> 6, lane = tid & 63;
  int mbase = blockIdx.x * 64;
  f32x4 acc[15];
  #pragma unroll
  for(int i=0;i<15;++i) acc[i] = (f32x4){0.f,0.f,0.f,0.f};
  int zrow = tid >> 2, zch = tid & 3;
  int r = lane & 15, q = lane >> 4;
  for(int k0=0; k0<KZ; k0+=32){
    uint4 zv = *(const uint4*)(Z + (size_t)(mbase+zrow)*KZ + k0 + zch*8);
    *(uint4*)&Zt[zrow*40 + zch*8] = zv;
    for(int idx=tid; idx<960; idx+=256){
      int row = idx >> 2, c4 = idx & 3;
      uint4 wv = *(const uint4*)(WcT + (size_t)row*KZ + k0 + c4*8);
      *(uint4*)&Wt[row*40 + c4*8] = wv;
    }
    __syncthreads();
    bf16x8 af = *(const bf16x8*)&Zt[(wave*16 + r)*40 + q*8];
    #pragma unroll
    for(int ct=0; ct<15; ++ct){
      bf16x8 bfv = *(const bf16x8*)&Wt[(ct*16 + r)*40 + q*8];
      acc[ct] = __builtin_amdgcn_mfma_f32_16x16x32_bf16(af, bfv, acc[ct], 0, 0, 0);
    }
    __syncthreads();
  }
  #pragma unroll
  for(int rr=0; rr<4; ++rr){
    int grow = mbase + wave*16 + q*4 + rr;
    if(grow < NN){
      float2 ab = sc[grow];
      #pragma unroll
      for(int ct=0; ct<5; ++ct){
        int c = ct*16 + r;
        float v = acc[ct][rr] + ab.x*acc[ct+5][rr] + ab.y*acc[ct+10][rr] + bias[c];
        outb[(size_t)grow*DD + c] = v;
      }
    }
  }
}

__global__ void k_bnstat(const float* __restrict__ outb, float* stats){
  int tid = threadIdx.x;
  if(tid >= 240) return;
  int c = tid % DD;
  int stripe = tid / DD;
  int S = gridDim.x * 3;
  float s=0.0f, qq=0.0f;
  for(int i = blockIdx.x*3 + stripe; i < NN; i += S){
    float v = outb[(size_t)i*DD + c];
    s += v; qq += v*v;
  }
  atomicAdd(&stats[c], s);
  atomicAdd(&stats[DD + c], qq);
}

__global__ void k_bnfin(const float* __restrict__ stats, float* murs){
  int c = threadIdx.x;
  if(c < DD){
    float mu = stats[c] / (float)NN;
    float var = stats[DD+c] / (float)NN - mu*mu;
    murs[c] = mu;
    murs[DD+c] = rsqrtf(var + 1e-5f);
  }
}

__global__ void k_apply(const float* __restrict__ outb, const float* __restrict__ murs,
                        const float* __restrict__ g_, const float* __restrict__ b_,
                        const float* __restrict__ xc, float* __restrict__ xn){
  int idx = blockIdx.x*blockDim.x + threadIdx.x;
  if(idx >= NN*DD) return;
  int c = idx % DD;
  float v = (outb[idx] - murs[c]) * murs[DD+c] * g_[c] + b_[c];
  v = fmaxf(v, 0.0f);
  xn[idx] = v + xc[idx];
}

// ---------------- head ----------------
__device__ __forceinline__ int lbound(const int* b, int n, int v){
  int lo=0, hi=n;
  while(lo < hi){ int mid = (lo+hi)>>1; if(b[mid] < v) lo = mid+1; else hi = mid; }
  return lo;
}

__global__ void k_pool(const float* __restrict__ xf, const int* __restrict__ batch,
                       float* __restrict__ pooled){
  int g = blockIdx.x;
  int c = threadIdx.x;
  if(c >= DD) return;
  int lo = lbound(batch, NN, g), hi = lbound(batch, NN, g+1);
  float s = 0.0f;
  for(int i=lo;i<hi;++i) s += xf[(size_t)i*DD + c];
  int cnt = hi - lo;
  pooled[g*DD + c] = s / (float)(cnt > 0 ? cnt : 1);
}

__global__ void k_mlp(const float* __restrict__ pooled,
                      const float* __restrict__ w1, const float* __restrict__ b1,
                      const float* __restrict__ w2, const float* __restrict__ b2,
                      const float* __restrict__ w3, const float* __restrict__ b3,
                      float* __restrict__ out){
  __shared__ float W1[80*40], B1[40], W2[40*20], B2[20], W3[20];
  for(int i=threadIdx.x;i<80*40;i+=256) W1[i]=w1[i];
  for(int i=threadIdx.x;i<40;i+=256)    B1[i]=b1[i];
  for(int i=threadIdx.x;i<40*20;i+=256) W2[i]=w2[i];
  for(int i=threadIdx.x;i<20;i+=256)    B2[i]=b2[i];
  if(threadIdx.x<20) W3[threadIdx.x]=w3[threadIdx.x];
  __syncthreads();
  int g = threadIdx.x;
  float h1[40];
  #pragma unroll
  for(int j=0;j<40;++j) h1[j] = B1[j];
  for(int cc=0; cc<80; ++cc){
    float x = pooled[g*DD + cc];
    #pragma unroll
    for(int j=0;j<40;++j) h1[j] += x * W1[cc*40 + j];
  }
  #pragma unroll
  for(int j=0;j<40;++j) h1[j] = fmaxf(h1[j], 0.0f);
  float h2[20];
  #pragma unroll
  for(int j=0;j<20;++j) h2[j] = B2[j];
  for(int cc=0; cc<40; ++cc){
    float x = h1[cc];
    #pragma unroll
    for(int j=0;j<20;++j) h2[j] += x * W2[cc*20 + j];
  }
  float o = b3[0];
  #pragma unroll
  for(int j=0;j<20;++j) o += fmaxf(h2[j], 0.0f) * W3[j];
  out[g] = o;
}

// ---------------- launch ----------------
extern "C" void kernel_launch(void* const* d_in, const int* in_sizes, int n_in,
                              void* d_out, int out_size, void* d_ws, size_t ws_size,
                              hipStream_t stream){
  const float* x0     = (const float*)d_in[0];
  const int*   ei     = (const int*)d_in[1];
  const float* ea     = (const float*)d_in[2];
  const float* PE     = (const float*)d_in[3];
  const int*   batch  = (const int*)d_in[5];
  const float* pe_w   = (const float*)d_in[6];
  const float* pe_b   = (const float*)d_in[7];
  const float* conv_w = (const float*)d_in[8];
  const float* conv_b = (const float*)d_in[9];
  const float* bn_g   = (const float*)d_in[10];
  const float* bn_b   = (const float*)d_in[11];
  const float* w1 = (const float*)d_in[12];
  const float* b1 = (const float*)d_in[13];
  const float* w2 = (const float*)d_in[14];
  const float* b2 = (const float*)d_in[15];
  const float* w3 = (const float*)d_in[16];
  const float* b3 = (const float*)d_in[17];
  float* dout = (float*)d_out;

  char* p = (char*)d_ws;
  auto alloc = [&](size_t bytes)->char*{
    char* r = p; p += (bytes + 255) & ~(size_t)255; return r;
  };
  int* deg  = (int*)alloc((size_t)NN*4);
  int* pos  = (int*)alloc((size_t)NN*4);
  int* off  = (int*)alloc((size_t)(NN+1)*4);
  int* esrc = (int*)alloc((size_t)NE*4);
  int* eid  = (int*)alloc((size_t)NE*4);
  float* ea_s = (float*)alloc((size_t)NE*EDIM*4);
  float* xp   = (float*)alloc((size_t)NN*DD*4);
  unsigned short* Z   = (unsigned short*)alloc((size_t)MPAD*KZ*2);
  unsigned short* WcT = (unsigned short*)alloc((size_t)NOUT*KZ*2);
  float* outb = (float*)alloc((size_t)NN*DD*4);
  float* xA   = (float*)alloc((size_t)NN*DD*4);
  float* xB   = (float*)alloc((size_t)NN*DD*4);
  float2* sc  = (float2*)alloc((size_t)NN*8);
  float* stats = (float*)alloc(160*4);
  float* murs  = (float*)alloc(160*4);
  float* pooled = (float*)alloc((size_t)NG*DD*4);

  k_setup<<<(NN + (MPAD-NN)*KZ + 255)/256, 256, 0, stream>>>(deg, Z);
  k_hist<<<(NE+255)/256, 256, 0, stream>>>(ei + NE, deg);
  k_scan<<<1, 1024, 0, stream>>>(deg, off, pos);
  k_fill<<<(NE+255)/256, 256, 0, stream>>>(ei, pos, esrc, eid);
  k_gather<<<(NE+255)/256, 256, 0, stream>>>(ea, eid, ea_s);

  const float* xc = x0;
  float* bufs[2] = {xA, xB};
  for(int l=0; l<NLAY; ++l){
    float* xn = bufs[l & 1];
    k_xp<<<(NN*DD+255)/256, 256, 0, stream>>>(xc, PE, pe_w + (size_t)l*PED*DD,
                                              pe_b + l*DD, xp);
    k_agg<<<(NN+7)/8, 256, 0, stream>>>(xp, ea_s, off, esrc, Z, sc);
    k_wprep<<<(NOUT*KZ+255)/256, 256, 0, stream>>>(conv_w + (size_t)l*2112*DD, WcT, stats);
    k_gemm<<<MPAD/64, 256, 0, stream>>>(Z, WcT, sc, conv_b + l*DD, outb);
    k_bnstat<<<64, 256, 0, stream>>>(outb, stats);
    k_bnfin<<<1, 128, 0, stream>>>(stats, murs);
    k_apply<<<(NN*DD+255)/256, 256, 0, stream>>>(outb, murs, bn_g + l*DD, bn_b + l*DD,
                                                 xc, xn);
    xc = xn;
  }
  k_pool<<<NG, 128, 0, stream>>>(xc, batch, pooled);
  k_mlp<<<1, 256, 0, stream>>>(pooled, w1, b1, w2, b2, w3, b3, dout);
}

// Round 2
// 1059.646 us; speedup vs baseline: 1.2728x; 1.2728x over previous
//
#include <hip/hip_runtime.h>
#include <stdint.h>

#define NN 50000
#define DD 80
#define NE 800000
#define EDIM 16
#define PED 37
#define NG 256
#define NLAY 4
#define KZ 480
#define NOUT 240
#define MPAD 50048
#define NBLK (MPAD/64)
#define NB 196
#define AVG_LD 1.4059212841460147f
#define S5 0.0031622776601683794f

typedef __bf16 bf16x8 __attribute__((ext_vector_type(8)));
typedef float f32x4 __attribute__((ext_vector_type(4)));

__device__ __forceinline__ unsigned short f2bf(float f){
  union { float f; unsigned u; } v; v.f = f;
  return (unsigned short)((v.u + 0x7fffu + ((v.u >> 16) & 1u)) >> 16);
}
__device__ __forceinline__ float bf2f(unsigned short u){
  union { unsigned u; float f; } v; v.u = ((unsigned)u) << 16; return v.f;
}

// ---------------- setup ----------------
__global__ void k_setup(int* deg, unsigned short* Z){
  int idx = blockIdx.x*blockDim.x + threadIdx.x;
  if(idx < NN) deg[idx] = 0;
  int t = idx - NN;
  if(t >= 0 && t < (MPAD-NN)*KZ) Z[(size_t)NN*KZ + t] = 0;
}

__global__ void k_hist(const int* __restrict__ tgt, int* deg){
  int e = blockIdx.x*blockDim.x + threadIdx.x;
  if(e < NE) atomicAdd(&deg[tgt[e]], 1);
}

// block partial sums
__global__ void k_scan1(const int* __restrict__ deg, int* bsum){
  __shared__ int red[256];
  int i = blockIdx.x*256 + threadIdx.x;
  int v = (i < NN) ? deg[i] : 0;
  red[threadIdx.x] = v; __syncthreads();
  for(int d=128; d>0; d>>=1){
    if(threadIdx.x < d) red[threadIdx.x] += red[threadIdx.x + d];
    __syncthreads();
  }
  if(threadIdx.x == 0) bsum[blockIdx.x] = red[0];
}

// scan block sums (1 block)
__global__ void k_scan2(const int* __restrict__ bsum, int* bbase, int* off){
  __shared__ int s[256];
  int t = threadIdx.x;
  int v = (t < NB) ? bsum[t] : 0;
  s[t] = v; __syncthreads();
  for(int d=1; d<256; d<<=1){
    int u = (t >= d) ? s[t-d] : 0;
    __syncthreads();
    s[t] += u;
    __syncthreads();
  }
  if(t < NB) bbase[t] = s[t] - v;
  if(t == NB-1) off[NN] = s[t];
}

// per-element offsets
__global__ void k_scan3(const int* __restrict__ deg, const int* __restrict__ bbase,
                        int* off, int* pos){
  __shared__ int s[256];
  int t = threadIdx.x;
  int i = blockIdx.x*256 + t;
  int v = (i < NN) ? deg[i] : 0;
  s[t] = v; __syncthreads();
  for(int d=1; d<256; d<<=1){
    int u = (t >= d) ? s[t-d] : 0;
    __syncthreads();
    s[t] += u;
    __syncthreads();
  }
  int excl = s[t] - v + bbase[blockIdx.x];
  if(i < NN){ off[i] = excl; pos[i] = excl; }
}

__global__ void k_fill(const int* __restrict__ ei, int* pos, int* esrc, int* eid){
  int e = blockIdx.x*blockDim.x + threadIdx.x;
  if(e < NE){
    int t = ei[NE + e];
    int idx = atomicAdd(&pos[t], 1);
    esrc[idx] = ei[e];
    eid[idx] = e;
  }
}

__global__ void k_gather(const float* __restrict__ ea, const int* __restrict__ eid,
                         unsigned short* __restrict__ ea_b){
  int j = blockIdx.x*blockDim.x + threadIdx.x;
  if(j >= NE) return;
  int e = eid[j];
  const float4* s = (const float4*)(ea + (size_t)e*EDIM);
  float4 f0=s[0], f1=s[1], f2=s[2], f3=s[3];
  unsigned short tmp[16];
  tmp[0]=f2bf(f0.x); tmp[1]=f2bf(f0.y); tmp[2]=f2bf(f0.z); tmp[3]=f2bf(f0.w);
  tmp[4]=f2bf(f1.x); tmp[5]=f2bf(f1.y); tmp[6]=f2bf(f1.z); tmp[7]=f2bf(f1.w);
  tmp[8]=f2bf(f2.x); tmp[9]=f2bf(f2.y); tmp[10]=f2bf(f2.z); tmp[11]=f2bf(f2.w);
  tmp[12]=f2bf(f3.x); tmp[13]=f2bf(f3.y); tmp[14]=f2bf(f3.z); tmp[15]=f2bf(f3.w);
  uint4* d = (uint4*)(ea_b + (size_t)j*EDIM);
  d[0] = *(uint4*)&tmp[0];
  d[1] = *(uint4*)&tmp[8];
}

// ---------------- per-layer ----------------
// layer-0 xp only (later layers fused into k_apply)
__global__ void k_xp(const float* __restrict__ xc, const float* __restrict__ PE,
                     const float* __restrict__ pw, const float* __restrict__ pb,
                     unsigned short* __restrict__ xpb){
  int idx = blockIdx.x*blockDim.x + threadIdx.x;
  if(idx >= NN*DD) return;
  int i = idx / DD, c = idx % DD;
  float s = xc[idx] + pb[c];
  const float* per = PE + (size_t)i*PED;
  for(int p=0;p<PED;++p) s += per[p]*pw[p*DD + c];
  xpb[idx] = f2bf(s);
}

__global__ __launch_bounds__(256) void k_agg(
    const unsigned short* __restrict__ xpb, const unsigned short* __restrict__ ea_b,
    const int* __restrict__ off, const int* __restrict__ esrc,
    unsigned short* __restrict__ Z, float2* __restrict__ sc){
  int g = blockIdx.x*8 + (threadIdx.x>>5);
  int t = threadIdx.x & 31;
  if(g >= NN) return;
  int lo = off[g], hi = off[g+1];
  int d = hi - lo;
  float s0=0,s1=0,s2=0,q0=0,q1=0,q2=0;
  float INF = __builtin_huge_valf();
  float mn0=INF,mn1=INF,mn2=INF,mx0=-INF,mx1=-INF,mx2=-INF;
  for(int j=lo;j<hi;++j){
    int sr = esrc[j];
    const unsigned short* xr = xpb + (size_t)sr*DD;
    float v0 = bf2f(xr[t]);
    float v1 = bf2f(xr[t+32]);
    float v2 = (t<16) ? bf2f(xr[64+t]) : bf2f(ea_b[(size_t)j*EDIM + (t-16)]);
    s0+=v0; q0+=v0*v0; mn0=fminf(mn0,v0); mx0=fmaxf(mx0,v0);
    s1+=v1; q1+=v1*v1; mn1=fminf(mn1,v1); mx1=fmaxf(mx1,v1);
    s2+=v2; q2+=v2*v2; mn2=fminf(mn2,v2); mx2=fmaxf(mx2,v2);
  }
  float dc = (float)(d>0?d:1);
  float inv = 1.0f/dc;
  float m0=s0*inv, m1=s1*inv, m2=s2*inv;
  float sd0 = sqrtf(fmaxf(q0*inv - m0*m0, 0.0f) + 1e-5f);
  float sd1 = sqrtf(fmaxf(q1*inv - m1*m1, 0.0f) + 1e-5f);
  float sd2 = sqrtf(fmaxf(q2*inv - m2*m2, 0.0f) + 1e-5f);
  if(d==0){ mn0=mn1=mn2=0.0f; mx0=mx1=mx2=0.0f; }
  unsigned short* zr = Z + (size_t)g*KZ;
  zr[t]      = f2bf(m0);  zr[t+32]     = f2bf(m1);  zr[t+64]     = f2bf(m2);
  zr[96+t]   = f2bf(mn0); zr[96+t+32]  = f2bf(mn1); zr[96+t+64]  = f2bf(mn2);
  zr[192+t]  = f2bf(mx0); zr[192+t+32] = f2bf(mx1); zr[192+t+64] = f2bf(mx2);
  zr[288+t]  = f2bf(sd0); zr[288+t+32] = f2bf(sd1); zr[288+t+64] = f2bf(sd2);
  const unsigned short* xg = xpb + (size_t)g*DD;
  unsigned short zz = 0;
  zr[384+t] = (d>0) ? xg[t] : zz;
  zr[416+t] = (d>0) ? xg[32+t] : zz;
  if(t<16) zr[448+t] = (d>0) ? xg[64+t] : zz;
  if(t==0) zr[464] = f2bf(1.0f);
  if(t>=1 && t<16) zr[464+t] = 0;
  if(t==16){
    float logd = logf(dc + 1.0f);
    sc[g] = make_float2(logd/AVG_LD, AVG_LD/logd);
  }
}

// build WcT [NOUT][KZ] bf16 from conv_w (layer slice)
__global__ void k_wprep(const float* __restrict__ cw, unsigned short* __restrict__ WcT){
  int idx = blockIdx.x*blockDim.x + threadIdx.x;
  if(idx >= NOUT*KZ) return;
  int j = idx / KZ;          // output col 0..239
  int r = idx % KZ;          // Z dim
  int ks = j / DD, c = j % DD;
  float val = 0.0f;
  if(r < 384){
    int stat = r/96, m = r%96;
    val = cw[(size_t)(ks*704 + stat*176 + 80 + m)*DD + c];
  } else if(r < 464){
    int m = r - 384;
    int b = ks*704 + m;
    val = cw[(size_t)b*DD + c] + cw[(size_t)(b+176)*DD + c] + cw[(size_t)(b+352)*DD + c];
  } else if(r == 464){
    float s = 0.0f; int b = ks*704 + 528;
    for(int m=0;m<80;++m) s += cw[(size_t)(b+m)*DD + c];
    val = S5 * s;
  }
  WcT[idx] = f2bf(val);
}

__global__ __launch_bounds__(256) void k_gemm(
    const unsigned short* __restrict__ Z, const unsigned short* __restrict__ WcT,
    const float2* __restrict__ sc, const float* __restrict__ bias,
    float* __restrict__ outb, float* __restrict__ partial){
  __shared__ __align__(16) unsigned short Zt[64*40];
  __shared__ __align__(16) unsigned short Wt[240*40];
  __shared__ float sred[4][160];
  int tid = threadIdx.x;
  int wave = tid >> 6, lane = tid & 63;
  int mbase = blockIdx.x * 64;
  f32x4 acc[15];
  #pragma unroll
  for(int i=0;i<15;++i) acc[i] = (f32x4){0.f,0.f,0.f,0.f};
  int zrow = tid >> 2, zch = tid & 3;
  int r = lane & 15, q = lane >> 4;
  for(int k0=0; k0<KZ; k0+=32){
    uint4 zv = *(const uint4*)(Z + (size_t)(mbase+zrow)*KZ + k0 + zch*8);
    *(uint4*)&Zt[zrow*40 + zch*8] = zv;
    for(int idx=tid; idx<960; idx+=256){
      int row = idx >> 2, c4 = idx & 3;
      uint4 wv = *(const uint4*)(WcT + (size_t)row*KZ + k0 + c4*8);
      *(uint4*)&Wt[row*40 + c4*8] = wv;
    }
    __syncthreads();
    bf16x8 af = *(const bf16x8*)&Zt[(wave*16 + r)*40 + q*8];
    #pragma unroll
    for(int ct=0; ct<15; ++ct){
      bf16x8 bfv = *(const bf16x8*)&Wt[(ct*16 + r)*40 + q*8];
      acc[ct] = __builtin_amdgcn_mfma_f32_16x16x32_bf16(af, bfv, acc[ct], 0, 0, 0);
    }
    __syncthreads();
  }
  float colS[5], colQ[5];
  #pragma unroll
  for(int ct=0; ct<5; ++ct){ colS[ct]=0.f; colQ[ct]=0.f; }
  #pragma unroll
  for(int rr=0; rr<4; ++rr){
    int grow = mbase + wave*16 + q*4 + rr;
    if(grow < NN){
      float2 ab = sc[grow];
      #pragma unroll
      for(int ct=0; ct<5; ++ct){
        int c = ct*16 + r;
        float v = acc[ct][rr] + ab.x*acc[ct+5][rr] + ab.y*acc[ct+10][rr] + bias[c];
        outb[(size_t)grow*DD + c] = v;
        colS[ct] += v; colQ[ct] += v*v;
      }
    }
  }
  #pragma unroll
  for(int ct=0; ct<5; ++ct){
    colS[ct] += __shfl_xor(colS[ct], 16, 64);
    colS[ct] += __shfl_xor(colS[ct], 32, 64);
    colQ[ct] += __shfl_xor(colQ[ct], 16, 64);
    colQ[ct] += __shfl_xor(colQ[ct], 32, 64);
  }
  if(q == 0){
    #pragma unroll
    for(int ct=0; ct<5; ++ct){
      int c = ct*16 + r;
      sred[wave][c] = colS[ct];
      sred[wave][80+c] = colQ[ct];
    }
  }
  __syncthreads();
  if(tid < 160){
    partial[(size_t)blockIdx.x*160 + tid] =
      sred[0][tid] + sred[1][tid] + sred[2][tid] + sred[3][tid];
  }
}

__global__ void k_bnfin(const float* __restrict__ partial, float* __restrict__ murs){
  __shared__ float red[1024];
  __shared__ float tot[160];
  int tid = threadIdx.x;
  int c = tid % 160, stripe = tid / 160;
  float s = 0.0f;
  if(tid < 960){
    for(int b=stripe; b<NBLK; b+=6) s += partial[(size_t)b*160 + c];
  }
  red[tid] = s; __syncthreads();
  if(tid < 160){
    float t2 = 0.0f;
    for(int k=0;k<6;++k) t2 += red[k*160 + tid];
    tot[tid] = t2;
  }
  __syncthreads();
  if(tid < 80){
    float mu = tot[tid] / (float)NN;
    float var = tot[80+tid] / (float)NN - mu*mu;
    murs[tid] = mu;
    murs[80+tid] = rsqrtf(var + 1e-5f);
  }
}

// BN-apply + relu + residual, fused with next layer's xp computation
__global__ void k_apply(const float* __restrict__ outb, const float* __restrict__ murs,
                        const float* __restrict__ g_, const float* __restrict__ b_,
                        const float* __restrict__ xc, float* __restrict__ xn,
                        const float* __restrict__ PE, const float* __restrict__ pwn,
                        const float* __restrict__ pbn, unsigned short* __restrict__ xpb,
                        int do_xp){
  int idx = blockIdx.x*blockDim.x + threadIdx.x;
  if(idx >= NN*DD) return;
  int i = idx / DD, c = idx % DD;
  float v = (outb[idx] - murs[c]) * murs[DD+c] * g_[c] + b_[c];
  v = fmaxf(v, 0.0f);
  float xnew = v + xc[idx];
  xn[idx] = xnew;
  if(do_xp){
    float s = xnew + pbn[c];
    const float* per = PE + (size_t)i*PED;
    for(int p=0;p<PED;++p) s += per[p]*pwn[p*DD + c];
    xpb[idx] = f2bf(s);
  }
}

// ---------------- head ----------------
__device__ __forceinline__ int lbound(const int* b, int n, int v){
  int lo=0, hi=n;
  while(lo < hi){ int mid = (lo+hi)>>1; if(b[mid] < v) lo = mid+1; else hi = mid; }
  return lo;
}

__global__ void k_pool(const float* __restrict__ xf, const int* __restrict__ batch,
                       float* __restrict__ pooled){
  int g = blockIdx.x;
  int c = threadIdx.x;
  if(c >= DD) return;
  int lo = lbound(batch, NN, g), hi = lbound(batch, NN, g+1);
  float s = 0.0f;
  for(int i=lo;i<hi;++i) s += xf[(size_t)i*DD + c];
  int cnt = hi - lo;
  pooled[g*DD + c] = s / (float)(cnt > 0 ? cnt : 1);
}

__global__ void k_mlp(const float* __restrict__ pooled,
                      const float* __restrict__ w1, const float* __restrict__ b1,
                      const float* __restrict__ w2, const float* __restrict__ b2,
                      const float* __restrict__ w3, const float* __restrict__ b3,
                      float* __restrict__ out){
  __shared__ float W1[80*40], B1[40], W2[40*20], B2[20], W3[20];
  for(int i=threadIdx.x;i<80*40;i+=256) W1[i]=w1[i];
  for(int i=threadIdx.x;i<40;i+=256)    B1[i]=b1[i];
  for(int i=threadIdx.x;i<40*20;i+=256) W2[i]=w2[i];
  for(int i=threadIdx.x;i<20;i+=256)    B2[i]=b2[i];
  if(threadIdx.x<20) W3[threadIdx.x]=w3[threadIdx.x];
  __syncthreads();
  int g = threadIdx.x;
  float h1[40];
  #pragma unroll
  for(int j=0;j<40;++j) h1[j] = B1[j];
  for(int cc=0; cc<80; ++cc){
    float x = pooled[g*DD + cc];
    #pragma unroll
    for(int j=0;j<40;++j) h1[j] += x * W1[cc*40 + j];
  }
  #pragma unroll
  for(int j=0;j<40;++j) h1[j] = fmaxf(h1[j], 0.0f);
  float h2[20];
  #pragma unroll
  for(int j=0;j<20;++j) h2[j] = B2[j];
  for(int cc=0; cc<40; ++cc){
    float x = h1[cc];
    #pragma unroll
    for(int j=0;j<20;++j) h2[j] += x * W2[cc*20 + j];
  }
  float o = b3[0];
  #pragma unroll
  for(int j=0;j<20;++j) o += fmaxf(h2[j], 0.0f) * W3[j];
  out[g] = o;
}

// ---------------- launch ----------------
extern "C" void kernel_launch(void* const* d_in, const int* in_sizes, int n_in,
                              void* d_out, int out_size, void* d_ws, size_t ws_size,
                              hipStream_t stream){
  const float* x0     = (const float*)d_in[0];
  const int*   ei     = (const int*)d_in[1];
  const float* ea     = (const float*)d_in[2];
  const float* PE     = (const float*)d_in[3];
  const int*   batch  = (const int*)d_in[5];
  const float* pe_w   = (const float*)d_in[6];
  const float* pe_b   = (const float*)d_in[7];
  const float* conv_w = (const float*)d_in[8];
  const float* conv_b = (const float*)d_in[9];
  const float* bn_g   = (const float*)d_in[10];
  const float* bn_b   = (const float*)d_in[11];
  const float* w1 = (const float*)d_in[12];
  const float* b1 = (const float*)d_in[13];
  const float* w2 = (const float*)d_in[14];
  const float* b2 = (const float*)d_in[15];
  const float* w3 = (const float*)d_in[16];
  const float* b3 = (const float*)d_in[17];
  float* dout = (float*)d_out;

  char* p = (char*)d_ws;
  auto alloc = [&](size_t bytes)->char*{
    char* r = p; p += (bytes + 255) & ~(size_t)255; return r;
  };
  int* deg  = (int*)alloc((size_t)NN*4);
  int* pos  = (int*)alloc((size_t)NN*4);
  int* off  = (int*)alloc((size_t)(NN+1)*4);
  int* bsum = (int*)alloc((size_t)NB*4);
  int* bbase= (int*)alloc((size_t)NB*4);
  int* esrc = (int*)alloc((size_t)NE*4);
  int* eid  = (int*)alloc((size_t)NE*4);
  unsigned short* ea_b = (unsigned short*)alloc((size_t)NE*EDIM*2);
  unsigned short* xpb  = (unsigned short*)alloc((size_t)NN*DD*2);
  unsigned short* Z    = (unsigned short*)alloc((size_t)MPAD*KZ*2);
  unsigned short* WcT  = (unsigned short*)alloc((size_t)NOUT*KZ*2);
  float* outb = (float*)alloc((size_t)NN*DD*4);
  float* xA   = (float*)alloc((size_t)NN*DD*4);
  float* xB   = (float*)alloc((size_t)NN*DD*4);
  float2* sc  = (float2*)alloc((size_t)NN*8);
  float* partial = (float*)alloc((size_t)NBLK*160*4);
  float* murs  = (float*)alloc(160*4);
  float* pooled = (float*)alloc((size_t)NG*DD*4);

  k_setup<<<(NN + (MPAD-NN)*KZ + 255)/256, 256, 0, stream>>>(deg, Z);
  k_hist<<<(NE+255)/256, 256, 0, stream>>>(ei + NE, deg);
  k_scan1<<<NB, 256, 0, stream>>>(deg, bsum);
  k_scan2<<<1, 256, 0, stream>>>(bsum, bbase, off);
  k_scan3<<<NB, 256, 0, stream>>>(deg, bbase, off, pos);
  k_fill<<<(NE+255)/256, 256, 0, stream>>>(ei, pos, esrc, eid);
  k_gather<<<(NE+255)/256, 256, 0, stream>>>(ea, eid, ea_b);

  k_xp<<<(NN*DD+255)/256, 256, 0, stream>>>(x0, PE, pe_w, pe_b, xpb);

  const float* xc = x0;
  float* bufs[2] = {xA, xB};
  for(int l=0; l<NLAY; ++l){
    float* xn = bufs[l & 1];
    k_agg<<<(NN+7)/8, 256, 0, stream>>>(xpb, ea_b, off, esrc, Z, sc);
    k_wprep<<<(NOUT*KZ+255)/256, 256, 0, stream>>>(conv_w + (size_t)l*2112*DD, WcT);
    k_gemm<<<NBLK, 256, 0, stream>>>(Z, WcT, sc, conv_b + l*DD, outb, partial);
    k_bnfin<<<1, 1024, 0, stream>>>(partial, murs);
    int do_xp = (l < NLAY-1) ? 1 : 0;
    k_apply<<<(NN*DD+255)/256, 256, 0, stream>>>(outb, murs, bn_g + l*DD, bn_b + l*DD,
                                                 xc, xn, PE,
                                                 pe_w + (size_t)(l+1 < NLAY ? l+1 : 0)*PED*DD,
                                                 pe_b + (l+1 < NLAY ? l+1 : 0)*DD,
                                                 xpb, do_xp);
    xc = xn;
  }
  k_pool<<<NG, 128, 0, stream>>>(xc, batch, pooled);
  k_mlp<<<1, 256, 0, stream>>>(pooled, w1, b1, w2, b2, w3, b3, dout);
}

// Round 3
// 898.170 us; speedup vs baseline: 1.5016x; 1.1798x over previous
//
#include <hip/hip_runtime.h>
#include <stdint.h>

#define NN 50000
#define DD 80
#define NE 800000
#define EDIM 16
#define PED 37
#define NG 256
#define NLAY 4
#define KZ 480
#define NOUT 240
#define MPAD 50048
#define NBLK (MPAD/128)
#define NB 196
#define AVG_LD 1.4059212841460147f
#define S5 0.0031622776601683794f

typedef __bf16 bf16x8 __attribute__((ext_vector_type(8)));
typedef float f32x4 __attribute__((ext_vector_type(4)));

__device__ __forceinline__ unsigned short f2bf(float f){
  union { float f; unsigned u; } v; v.f = f;
  return (unsigned short)((v.u + 0x7fffu + ((v.u >> 16) & 1u)) >> 16);
}
__device__ __forceinline__ float bf2f(unsigned short u){
  union { unsigned u; float f; } v; v.u = ((unsigned)u) << 16; return v.f;
}

// ---------------- setup ----------------
__global__ void k_setup(int* deg, unsigned short* Z){
  int idx = blockIdx.x*blockDim.x + threadIdx.x;
  if(idx < NN) deg[idx] = 0;
  int t = idx - NN;
  if(t >= 0 && t < (MPAD-NN)*KZ) Z[(size_t)NN*KZ + t] = 0;
}

__global__ void k_hist(const int* __restrict__ tgt, int* deg){
  int e = blockIdx.x*blockDim.x + threadIdx.x;
  if(e < NE) atomicAdd(&deg[tgt[e]], 1);
}

// block partial sums
__global__ void k_scan1(const int* __restrict__ deg, int* bsum){
  __shared__ int red[256];
  int i = blockIdx.x*256 + threadIdx.x;
  int v = (i < NN) ? deg[i] : 0;
  red[threadIdx.x] = v; __syncthreads();
  for(int d=128; d>0; d>>=1){
    if(threadIdx.x < d) red[threadIdx.x] += red[threadIdx.x + d];
    __syncthreads();
  }
  if(threadIdx.x == 0) bsum[blockIdx.x] = red[0];
}

// scan block sums (1 block)
__global__ void k_scan2(const int* __restrict__ bsum, int* bbase, int* off){
  __shared__ int s[256];
  int t = threadIdx.x;
  int v = (t < NB) ? bsum[t] : 0;
  s[t] = v; __syncthreads();
  for(int d=1; d<256; d<<=1){
    int u = (t >= d) ? s[t-d] : 0;
    __syncthreads();
    s[t] += u;
    __syncthreads();
  }
  if(t < NB) bbase[t] = s[t] - v;
  if(t == NB-1) off[NN] = s[t];
}

// per-element offsets
__global__ void k_scan3(const int* __restrict__ deg, const int* __restrict__ bbase,
                        int* off, int* pos){
  __shared__ int s[256];
  int t = threadIdx.x;
  int i = blockIdx.x*256 + t;
  int v = (i < NN) ? deg[i] : 0;
  s[t] = v; __syncthreads();
  for(int d=1; d<256; d<<=1){
    int u = (t >= d) ? s[t-d] : 0;
    __syncthreads();
    s[t] += u;
    __syncthreads();
  }
  int excl = s[t] - v + bbase[blockIdx.x];
  if(i < NN){ off[i] = excl; pos[i] = excl; }
}

__global__ void k_fill(const int* __restrict__ ei, int* pos, int* esrc, int* eid){
  int e = blockIdx.x*blockDim.x + threadIdx.x;
  if(e < NE){
    int t = ei[NE + e];
    int idx = atomicAdd(&pos[t], 1);
    esrc[idx] = ei[e];
    eid[idx] = e;
  }
}

__global__ void k_gather(const float* __restrict__ ea, const int* __restrict__ eid,
                         unsigned short* __restrict__ ea_b){
  int j = blockIdx.x*blockDim.x + threadIdx.x;
  if(j >= NE) return;
  int e = eid[j];
  const float4* s = (const float4*)(ea + (size_t)e*EDIM);
  float4 f0=s[0], f1=s[1], f2=s[2], f3=s[3];
  unsigned short tmp[16];
  tmp[0]=f2bf(f0.x); tmp[1]=f2bf(f0.y); tmp[2]=f2bf(f0.z); tmp[3]=f2bf(f0.w);
  tmp[4]=f2bf(f1.x); tmp[5]=f2bf(f1.y); tmp[6]=f2bf(f1.z); tmp[7]=f2bf(f1.w);
  tmp[8]=f2bf(f2.x); tmp[9]=f2bf(f2.y); tmp[10]=f2bf(f2.z); tmp[11]=f2bf(f2.w);
  tmp[12]=f2bf(f3.x); tmp[13]=f2bf(f3.y); tmp[14]=f2bf(f3.z); tmp[15]=f2bf(f3.w);
  uint4* d = (uint4*)(ea_b + (size_t)j*EDIM);
  d[0] = *(uint4*)&tmp[0];
  d[1] = *(uint4*)&tmp[8];
}

// ---------------- per-layer ----------------
// layer-0 xp only (later layers fused into k_apply)
__global__ void k_xp(const float* __restrict__ xc, const float* __restrict__ PE,
                     const float* __restrict__ pw, const float* __restrict__ pb,
                     unsigned short* __restrict__ xpb){
  int idx = blockIdx.x*blockDim.x + threadIdx.x;
  if(idx >= NN*DD) return;
  int i = idx / DD, c = idx % DD;
  float s = xc[idx] + pb[c];
  const float* per = PE + (size_t)i*PED;
  for(int p=0;p<PED;++p) s += per[p]*pw[p*DD + c];
  xpb[idx] = f2bf(s);
}

__global__ __launch_bounds__(256) void k_agg(
    const unsigned short* __restrict__ xpb, const unsigned short* __restrict__ ea_b,
    const int* __restrict__ off, const int* __restrict__ esrc,
    unsigned short* __restrict__ Z, float2* __restrict__ sc){
  int g = blockIdx.x*8 + (threadIdx.x>>5);
  int t = threadIdx.x & 31;
  if(g >= NN) return;
  int lo = off[g], hi = off[g+1];
  int d = hi - lo;
  float s0=0,s1=0,s2=0,q0=0,q1=0,q2=0;
  float INF = __builtin_huge_valf();
  float mn0=INF,mn1=INF,mn2=INF,mx0=-INF,mx1=-INF,mx2=-INF;
  for(int j=lo;j<hi;++j){
    int sr = esrc[j];
    const unsigned short* xr = xpb + (size_t)sr*DD;
    float v0 = bf2f(xr[t]);
    float v1 = bf2f(xr[t+32]);
    float v2 = (t<16) ? bf2f(xr[64+t]) : bf2f(ea_b[(size_t)j*EDIM + (t-16)]);
    s0+=v0; q0+=v0*v0; mn0=fminf(mn0,v0); mx0=fmaxf(mx0,v0);
    s1+=v1; q1+=v1*v1; mn1=fminf(mn1,v1); mx1=fmaxf(mx1,v1);
    s2+=v2; q2+=v2*v2; mn2=fminf(mn2,v2); mx2=fmaxf(mx2,v2);
  }
  float dc = (float)(d>0?d:1);
  float inv = 1.0f/dc;
  float m0=s0*inv, m1=s1*inv, m2=s2*inv;
  float sd0 = sqrtf(fmaxf(q0*inv - m0*m0, 0.0f) + 1e-5f);
  float sd1 = sqrtf(fmaxf(q1*inv - m1*m1, 0.0f) + 1e-5f);
  float sd2 = sqrtf(fmaxf(q2*inv - m2*m2, 0.0f) + 1e-5f);
  if(d==0){ mn0=mn1=mn2=0.0f; mx0=mx1=mx2=0.0f; }
  unsigned short* zr = Z + (size_t)g*KZ;
  zr[t]      = f2bf(m0);  zr[t+32]     = f2bf(m1);  zr[t+64]     = f2bf(m2);
  zr[96+t]   = f2bf(mn0); zr[96+t+32]  = f2bf(mn1); zr[96+t+64]  = f2bf(mn2);
  zr[192+t]  = f2bf(mx0); zr[192+t+32] = f2bf(mx1); zr[192+t+64] = f2bf(mx2);
  zr[288+t]  = f2bf(sd0); zr[288+t+32] = f2bf(sd1); zr[288+t+64] = f2bf(sd2);
  const unsigned short* xg = xpb + (size_t)g*DD;
  unsigned short zz = 0;
  zr[384+t] = (d>0) ? xg[t] : zz;
  zr[416+t] = (d>0) ? xg[32+t] : zz;
  if(t<16) zr[448+t] = (d>0) ? xg[64+t] : zz;
  if(t==0) zr[464] = f2bf(1.0f);
  if(t>=1 && t<16) zr[464+t] = 0;
  if(t==16){
    float logd = logf(dc + 1.0f);
    sc[g] = make_float2(logd/AVG_LD, AVG_LD/logd);
  }
}

// build WcT [NOUT][KZ] bf16 from conv_w (layer slice)
__global__ void k_wprep(const float* __restrict__ cw, unsigned short* __restrict__ WcT){
  int idx = blockIdx.x*blockDim.x + threadIdx.x;
  if(idx >= NOUT*KZ) return;
  int j = idx / KZ;          // output col 0..239
  int r = idx % KZ;          // Z dim
  int ks = j / DD, c = j % DD;
  float val = 0.0f;
  if(r < 384){
    int stat = r/96, m = r%96;
    val = cw[(size_t)(ks*704 + stat*176 + 80 + m)*DD + c];
  } else if(r < 464){
    int m = r - 384;
    int b = ks*704 + m;
    val = cw[(size_t)b*DD + c] + cw[(size_t)(b+176)*DD + c] + cw[(size_t)(b+352)*DD + c];
  } else if(r == 464){
    float s = 0.0f; int b = ks*704 + 528;
    for(int m=0;m<80;++m) s += cw[(size_t)(b+m)*DD + c];
    val = S5 * s;
  }
  WcT[idx] = f2bf(val);
}

// LDS-free GEMM: fragments loaded directly from global (W is L2-resident, Z block-private)
__global__ __launch_bounds__(256) void k_gemm(
    const unsigned short* __restrict__ Z, const unsigned short* __restrict__ WcT,
    const float2* __restrict__ sc, const float* __restrict__ bias,
    float* __restrict__ outb, float* __restrict__ partial){
  __shared__ float sred[4][160];
  int tid = threadIdx.x;
  int wave = tid >> 6, lane = tid & 63;
  int r = lane & 15, q = lane >> 4;
  int m0 = blockIdx.x*128 + wave*32;
  const unsigned short* Ap = Z + (size_t)(m0 + r)*KZ + q*8;
  const unsigned short* Bp = WcT + (size_t)r*KZ + q*8;
  f32x4 acc0[15], acc1[15];
  #pragma unroll
  for(int i=0;i<15;++i){ acc0[i]=(f32x4){0.f,0.f,0.f,0.f}; acc1[i]=(f32x4){0.f,0.f,0.f,0.f}; }
  #pragma unroll 1
  for(int k0=0; k0<KZ; k0+=32){
    bf16x8 a0 = *(const bf16x8*)(Ap + k0);
    bf16x8 a1 = *(const bf16x8*)(Ap + 16*KZ + k0);
    #pragma unroll
    for(int ct=0; ct<15; ++ct){
      bf16x8 b = *(const bf16x8*)(Bp + (size_t)ct*16*KZ + k0);
      acc0[ct] = __builtin_amdgcn_mfma_f32_16x16x32_bf16(a0, b, acc0[ct], 0, 0, 0);
      acc1[ct] = __builtin_amdgcn_mfma_f32_16x16x32_bf16(a1, b, acc1[ct], 0, 0, 0);
    }
  }
  float colS[5], colQ[5];
  #pragma unroll
  for(int ct=0; ct<5; ++ct){ colS[ct]=0.f; colQ[ct]=0.f; }
  #pragma unroll
  for(int rr=0; rr<4; ++rr){
    int grow = m0 + q*4 + rr;
    if(grow < NN){
      float2 ab = sc[grow];
      #pragma unroll
      for(int ct=0; ct<5; ++ct){
        int c = ct*16 + r;
        float v = acc0[ct][rr] + ab.x*acc0[ct+5][rr] + ab.y*acc0[ct+10][rr] + bias[c];
        outb[(size_t)grow*DD + c] = v;
        colS[ct] += v; colQ[ct] += v*v;
      }
    }
  }
  #pragma unroll
  for(int rr=0; rr<4; ++rr){
    int grow = m0 + 16 + q*4 + rr;
    if(grow < NN){
      float2 ab = sc[grow];
      #pragma unroll
      for(int ct=0; ct<5; ++ct){
        int c = ct*16 + r;
        float v = acc1[ct][rr] + ab.x*acc1[ct+5][rr] + ab.y*acc1[ct+10][rr] + bias[c];
        outb[(size_t)grow*DD + c] = v;
        colS[ct] += v; colQ[ct] += v*v;
      }
    }
  }
  #pragma unroll
  for(int ct=0; ct<5; ++ct){
    colS[ct] += __shfl_xor(colS[ct], 16, 64);
    colS[ct] += __shfl_xor(colS[ct], 32, 64);
    colQ[ct] += __shfl_xor(colQ[ct], 16, 64);
    colQ[ct] += __shfl_xor(colQ[ct], 32, 64);
  }
  if(q == 0){
    #pragma unroll
    for(int ct=0; ct<5; ++ct){
      int c = ct*16 + r;
      sred[wave][c] = colS[ct];
      sred[wave][80+c] = colQ[ct];
    }
  }
  __syncthreads();
  if(tid < 160){
    partial[(size_t)blockIdx.x*160 + tid] =
      sred[0][tid] + sred[1][tid] + sred[2][tid] + sred[3][tid];
  }
}

__global__ void k_bnfin(const float* __restrict__ partial, float* __restrict__ murs){
  __shared__ float red[1024];
  __shared__ float tot[160];
  int tid = threadIdx.x;
  int c = tid % 160, stripe = tid / 160;
  float s = 0.0f;
  if(tid < 960){
    for(int b=stripe; b<NBLK; b+=6) s += partial[(size_t)b*160 + c];
  }
  red[tid] = s; __syncthreads();
  if(tid < 160){
    float t2 = 0.0f;
    for(int k=0;k<6;++k) t2 += red[k*160 + tid];
    tot[tid] = t2;
  }
  __syncthreads();
  if(tid < 80){
    float mu = tot[tid] / (float)NN;
    float var = tot[80+tid] / (float)NN - mu*mu;
    murs[tid] = mu;
    murs[80+tid] = rsqrtf(var + 1e-5f);
  }
}

// BN-apply + relu + residual, fused with next layer's xp computation
__global__ void k_apply(const float* __restrict__ outb, const float* __restrict__ murs,
                        const float* __restrict__ g_, const float* __restrict__ b_,
                        const float* __restrict__ xc, float* __restrict__ xn,
                        const float* __restrict__ PE, const float* __restrict__ pwn,
                        const float* __restrict__ pbn, unsigned short* __restrict__ xpb,
                        int do_xp){
  int idx = blockIdx.x*blockDim.x + threadIdx.x;
  if(idx >= NN*DD) return;
  int i = idx / DD, c = idx % DD;
  float v = (outb[idx] - murs[c]) * murs[DD+c] * g_[c] + b_[c];
  v = fmaxf(v, 0.0f);
  float xnew = v + xc[idx];
  xn[idx] = xnew;
  if(do_xp){
    float s = xnew + pbn[c];
    const float* per = PE + (size_t)i*PED;
    for(int p=0;p<PED;++p) s += per[p]*pwn[p*DD + c];
    xpb[idx] = f2bf(s);
  }
}

// ---------------- head ----------------
__device__ __forceinline__ int lbound(const int* b, int n, int v){
  int lo=0, hi=n;
  while(lo < hi){ int mid = (lo+hi)>>1; if(b[mid] < v) lo = mid+1; else hi = mid; }
  return lo;
}

__global__ void k_pool(const float* __restrict__ xf, const int* __restrict__ batch,
                       float* __restrict__ pooled){
  int g = blockIdx.x;
  int c = threadIdx.x;
  if(c >= DD) return;
  int lo = lbound(batch, NN, g), hi = lbound(batch, NN, g+1);
  float s = 0.0f;
  for(int i=lo;i<hi;++i) s += xf[(size_t)i*DD + c];
  int cnt = hi - lo;
  pooled[g*DD + c] = s / (float)(cnt > 0 ? cnt : 1);
}

__global__ void k_mlp(const float* __restrict__ pooled,
                      const float* __restrict__ w1, const float* __restrict__ b1,
                      const float* __restrict__ w2, const float* __restrict__ b2,
                      const float* __restrict__ w3, const float* __restrict__ b3,
                      float* __restrict__ out){
  __shared__ float W1[80*40], B1[40], W2[40*20], B2[20], W3[20];
  for(int i=threadIdx.x;i<80*40;i+=256) W1[i]=w1[i];
  for(int i=threadIdx.x;i<40;i+=256)    B1[i]=b1[i];
  for(int i=threadIdx.x;i<40*20;i+=256) W2[i]=w2[i];
  for(int i=threadIdx.x;i<20;i+=256)    B2[i]=b2[i];
  if(threadIdx.x<20) W3[threadIdx.x]=w3[threadIdx.x];
  __syncthreads();
  int g = threadIdx.x;
  float h1[40];
  #pragma unroll
  for(int j=0;j<40;++j) h1[j] = B1[j];
  for(int cc=0; cc<80; ++cc){
    float x = pooled[g*DD + cc];
    #pragma unroll
    for(int j=0;j<40;++j) h1[j] += x * W1[cc*40 + j];
  }
  #pragma unroll
  for(int j=0;j<40;++j) h1[j] = fmaxf(h1[j], 0.0f);
  float h2[20];
  #pragma unroll
  for(int j=0;j<20;++j) h2[j] = B2[j];
  for(int cc=0; cc<40; ++cc){
    float x = h1[cc];
    #pragma unroll
    for(int j=0;j<20;++j) h2[j] += x * W2[cc*20 + j];
  }
  float o = b3[0];
  #pragma unroll
  for(int j=0;j<20;++j) o += fmaxf(h2[j], 0.0f) * W3[j];
  out[g] = o;
}

// ---------------- launch ----------------
extern "C" void kernel_launch(void* const* d_in, const int* in_sizes, int n_in,
                              void* d_out, int out_size, void* d_ws, size_t ws_size,
                              hipStream_t stream){
  const float* x0     = (const float*)d_in[0];
  const int*   ei     = (const int*)d_in[1];
  const float* ea     = (const float*)d_in[2];
  const float* PE     = (const float*)d_in[3];
  const int*   batch  = (const int*)d_in[5];
  const float* pe_w   = (const float*)d_in[6];
  const float* pe_b   = (const float*)d_in[7];
  const float* conv_w = (const float*)d_in[8];
  const float* conv_b = (const float*)d_in[9];
  const float* bn_g   = (const float*)d_in[10];
  const float* bn_b   = (const float*)d_in[11];
  const float* w1 = (const float*)d_in[12];
  const float* b1 = (const float*)d_in[13];
  const float* w2 = (const float*)d_in[14];
  const float* b2 = (const float*)d_in[15];
  const float* w3 = (const float*)d_in[16];
  const float* b3 = (const float*)d_in[17];
  float* dout = (float*)d_out;

  char* p = (char*)d_ws;
  auto alloc = [&](size_t bytes)->char*{
    char* r = p; p += (bytes + 255) & ~(size_t)255; return r;
  };
  int* deg  = (int*)alloc((size_t)NN*4);
  int* pos  = (int*)alloc((size_t)NN*4);
  int* off  = (int*)alloc((size_t)(NN+1)*4);
  int* bsum = (int*)alloc((size_t)NB*4);
  int* bbase= (int*)alloc((size_t)NB*4);
  int* esrc = (int*)alloc((size_t)NE*4);
  int* eid  = (int*)alloc((size_t)NE*4);
  unsigned short* ea_b = (unsigned short*)alloc((size_t)NE*EDIM*2);
  unsigned short* xpb  = (unsigned short*)alloc((size_t)NN*DD*2);
  unsigned short* Z    = (unsigned short*)alloc((size_t)MPAD*KZ*2);
  unsigned short* WcT  = (unsigned short*)alloc((size_t)NOUT*KZ*2);
  float* outb = (float*)alloc((size_t)NN*DD*4);
  float* xA   = (float*)alloc((size_t)NN*DD*4);
  float* xB   = (float*)alloc((size_t)NN*DD*4);
  float2* sc  = (float2*)alloc((size_t)MPAD*8);
  float* partial = (float*)alloc((size_t)NBLK*160*4);
  float* murs  = (float*)alloc(160*4);
  float* pooled = (float*)alloc((size_t)NG*DD*4);

  k_setup<<<(NN + (MPAD-NN)*KZ + 255)/256, 256, 0, stream>>>(deg, Z);
  k_hist<<<(NE+255)/256, 256, 0, stream>>>(ei + NE, deg);
  k_scan1<<<NB, 256, 0, stream>>>(deg, bsum);
  k_scan2<<<1, 256, 0, stream>>>(bsum, bbase, off);
  k_scan3<<<NB, 256, 0, stream>>>(deg, bbase, off, pos);
  k_fill<<<(NE+255)/256, 256, 0, stream>>>(ei, pos, esrc, eid);
  k_gather<<<(NE+255)/256, 256, 0, stream>>>(ea, eid, ea_b);

  k_xp<<<(NN*DD+255)/256, 256, 0, stream>>>(x0, PE, pe_w, pe_b, xpb);

  const float* xc = x0;
  float* bufs[2] = {xA, xB};
  for(int l=0; l<NLAY; ++l){
    float* xn = bufs[l & 1];
    k_agg<<<(NN+7)/8, 256, 0, stream>>>(xpb, ea_b, off, esrc, Z, sc);
    k_wprep<<<(NOUT*KZ+255)/256, 256, 0, stream>>>(conv_w + (size_t)l*2112*DD, WcT);
    k_gemm<<<NBLK, 256, 0, stream>>>(Z, WcT, sc, conv_b + l*DD, outb, partial);
    k_bnfin<<<1, 1024, 0, stream>>>(partial, murs);
    int do_xp = (l < NLAY-1) ? 1 : 0;
    k_apply<<<(NN*DD+255)/256, 256, 0, stream>>>(outb, murs, bn_g + l*DD, bn_b + l*DD,
                                                 xc, xn, PE,
                                                 pe_w + (size_t)(l+1 < NLAY ? l+1 : 0)*PED*DD,
                                                 pe_b + (l+1 < NLAY ? l+1 : 0)*DD,
                                                 xpb, do_xp);
    xc = xn;
  }
  k_pool<<<NG, 128, 0, stream>>>(xc, batch, pooled);
  k_mlp<<<1, 256, 0, stream>>>(pooled, w1, b1, w2, b2, w3, b3, dout);
}

// Round 4
// 817.475 us; speedup vs baseline: 1.6498x; 1.0987x over previous
//
#include <hip/hip_runtime.h>
#include <stdint.h>

#define NN 50000
#define DD 80
#define NE 800000
#define EDIM 16
#define PED 37
#define NG 256
#define NLAY 4
#define KZ 480
#define NOUT 240
#define MPAD 50048
#define NBLK (MPAD/128)
#define NB 196
#define AVG_LD 1.4059212841460147f
#define S5 0.0031622776601683794f

typedef __bf16 bf16x8 __attribute__((ext_vector_type(8)));
typedef float f32x4 __attribute__((ext_vector_type(4)));

__device__ __forceinline__ unsigned short f2bf(float f){
  union { float f; unsigned u; } v; v.f = f;
  return (unsigned short)((v.u + 0x7fffu + ((v.u >> 16) & 1u)) >> 16);
}
__device__ __forceinline__ float bf2f(unsigned short u){
  union { unsigned u; float f; } v; v.u = ((unsigned)u) << 16; return v.f;
}
__device__ __forceinline__ unsigned packbf(float a, float b){
  return (unsigned)f2bf(a) | ((unsigned)f2bf(b) << 16);
}

// ---------------- setup ----------------
__global__ void k_setup(int* deg, unsigned short* Z){
  int idx = blockIdx.x*blockDim.x + threadIdx.x;
  if(idx < NN) deg[idx] = 0;
  int t = idx - NN;
  if(t >= 0 && t < (MPAD-NN)*KZ) Z[(size_t)NN*KZ + t] = 0;
}

__global__ void k_hist(const int* __restrict__ tgt, int* deg){
  int e = blockIdx.x*blockDim.x + threadIdx.x;
  if(e < NE) atomicAdd(&deg[tgt[e]], 1);
}

__global__ void k_scan1(const int* __restrict__ deg, int* bsum){
  __shared__ int red[256];
  int i = blockIdx.x*256 + threadIdx.x;
  int v = (i < NN) ? deg[i] : 0;
  red[threadIdx.x] = v; __syncthreads();
  for(int d=128; d>0; d>>=1){
    if(threadIdx.x < d) red[threadIdx.x] += red[threadIdx.x + d];
    __syncthreads();
  }
  if(threadIdx.x == 0) bsum[blockIdx.x] = red[0];
}

__global__ void k_scan2(const int* __restrict__ bsum, int* bbase, int* off){
  __shared__ int s[256];
  int t = threadIdx.x;
  int v = (t < NB) ? bsum[t] : 0;
  s[t] = v; __syncthreads();
  for(int d=1; d<256; d<<=1){
    int u = (t >= d) ? s[t-d] : 0;
    __syncthreads();
    s[t] += u;
    __syncthreads();
  }
  if(t < NB) bbase[t] = s[t] - v;
  if(t == NB-1) off[NN] = s[t];
}

__global__ void k_scan3(const int* __restrict__ deg, const int* __restrict__ bbase,
                        int* off, int* pos){
  __shared__ int s[256];
  int t = threadIdx.x;
  int i = blockIdx.x*256 + t;
  int v = (i < NN) ? deg[i] : 0;
  s[t] = v; __syncthreads();
  for(int d=1; d<256; d<<=1){
    int u = (t >= d) ? s[t-d] : 0;
    __syncthreads();
    s[t] += u;
    __syncthreads();
  }
  int excl = s[t] - v + bbase[blockIdx.x];
  if(i < NN){ off[i] = excl; pos[i] = excl; }
}

// fill CSR: scatter src index AND edge_attr (bf16) in one pass
__global__ void k_fill(const int* __restrict__ ei, const float* __restrict__ ea,
                       int* pos, int* esrc, unsigned short* __restrict__ ea_b){
  int e = blockIdx.x*blockDim.x + threadIdx.x;
  if(e >= NE) return;
  int t = ei[NE + e];
  int idx = atomicAdd(&pos[t], 1);
  esrc[idx] = ei[e];
  const float4* s = (const float4*)(ea + (size_t)e*EDIM);
  float4 f0=s[0], f1=s[1], f2=s[2], f3=s[3];
  unsigned short tmp[16];
  tmp[0]=f2bf(f0.x); tmp[1]=f2bf(f0.y); tmp[2]=f2bf(f0.z); tmp[3]=f2bf(f0.w);
  tmp[4]=f2bf(f1.x); tmp[5]=f2bf(f1.y); tmp[6]=f2bf(f1.z); tmp[7]=f2bf(f1.w);
  tmp[8]=f2bf(f2.x); tmp[9]=f2bf(f2.y); tmp[10]=f2bf(f2.z); tmp[11]=f2bf(f2.w);
  tmp[12]=f2bf(f3.x); tmp[13]=f2bf(f3.y); tmp[14]=f2bf(f3.z); tmp[15]=f2bf(f3.w);
  uint4* d = (uint4*)(ea_b + (size_t)idx*EDIM);
  d[0] = *(uint4*)&tmp[0];
  d[1] = *(uint4*)&tmp[8];
}

// ---------------- per-layer ----------------
__global__ void k_xp(const float* __restrict__ xc, const float* __restrict__ PE,
                     const float* __restrict__ pw, const float* __restrict__ pb,
                     unsigned short* __restrict__ xpb){
  int idx = blockIdx.x*blockDim.x + threadIdx.x;
  if(idx >= NN*DD) return;
  int i = idx / DD, c = idx % DD;
  float s = xc[idx] + pb[c];
  const float* per = PE + (size_t)i*PED;
  for(int p=0;p<PED;++p) s += per[p]*pw[p*DD + c];
  xpb[idx] = f2bf(s);
}

// one 64-lane wave per node; halves process even/odd edges, combined by shfl_xor(32).
// lane (t = lane&31) owns channels {2t, 2t+1, 64+t}  (64+t maps to xp ch 64..79 for
// t<16 and edge_attr ch 0..15 -> logical ch 80..95 for t>=16).
__global__ __launch_bounds__(256) void k_agg(
    const unsigned short* __restrict__ xpb, const unsigned short* __restrict__ ea_b,
    const int* __restrict__ off, const int* __restrict__ esrc,
    unsigned short* __restrict__ Z, float2* __restrict__ sc){
  int g = blockIdx.x*4 + (threadIdx.x >> 6);
  if(g >= NN) return;
  int lane = threadIdx.x & 63;
  int h = lane >> 5, t = lane & 31;
  int lo = off[g], hi = off[g+1];
  int d = hi - lo;
  float s0=0,s1=0,s2=0,q0=0,q1=0,q2=0;
  const float INF = __builtin_huge_valf();
  float mn0=INF,mn1=INF,mn2=INF,mx0=-INF,mx1=-INF,mx2=-INF;

  auto edge = [&](int j){
    int sr = esrc[j];
    const unsigned* xr32 = (const unsigned*)(xpb + (size_t)sr*DD);
    unsigned w = xr32[t];
    union {unsigned u; float f;} ua, ub;
    ua.u = w << 16; ub.u = w & 0xffff0000u;
    float v0 = ua.f, v1 = ub.f;
    unsigned short u2 = (t < 16) ? xpb[(size_t)sr*DD + 64 + t]
                                 : ea_b[(size_t)j*EDIM + (t - 16)];
    float v2 = bf2f(u2);
    s0+=v0; q0+=v0*v0; mn0=fminf(mn0,v0); mx0=fmaxf(mx0,v0);
    s1+=v1; q1+=v1*v1; mn1=fminf(mn1,v1); mx1=fmaxf(mx1,v1);
    s2+=v2; q2+=v2*v2; mn2=fminf(mn2,v2); mx2=fmaxf(mx2,v2);
  };
  int j = lo + h;
  for(; j + 2 < hi; j += 4){ edge(j); edge(j+2); }
  if(j < hi) edge(j);

  s0 += __shfl_xor(s0,32,64); s1 += __shfl_xor(s1,32,64); s2 += __shfl_xor(s2,32,64);
  q0 += __shfl_xor(q0,32,64); q1 += __shfl_xor(q1,32,64); q2 += __shfl_xor(q2,32,64);
  mn0 = fminf(mn0, __shfl_xor(mn0,32,64));
  mn1 = fminf(mn1, __shfl_xor(mn1,32,64));
  mn2 = fminf(mn2, __shfl_xor(mn2,32,64));
  mx0 = fmaxf(mx0, __shfl_xor(mx0,32,64));
  mx1 = fmaxf(mx1, __shfl_xor(mx1,32,64));
  mx2 = fmaxf(mx2, __shfl_xor(mx2,32,64));

  float dc = (float)(d>0?d:1);
  float inv = 1.0f/dc;
  float m0=s0*inv, m1=s1*inv, m2=s2*inv;
  float sd0 = sqrtf(fmaxf(q0*inv - m0*m0, 0.0f) + 1e-5f);
  float sd1 = sqrtf(fmaxf(q1*inv - m1*m1, 0.0f) + 1e-5f);
  float sd2 = sqrtf(fmaxf(q2*inv - m2*m2, 0.0f) + 1e-5f);
  if(d==0){ mn0=mn1=mn2=0.0f; mx0=mx1=mx2=0.0f; }

  unsigned* zr32 = (unsigned*)(Z + (size_t)g*KZ);
  unsigned short* zr = (unsigned short*)zr32;
  if(h == 0){
    zr32[t]       = packbf(m0, m1);
    zr32[48 + t]  = packbf(mn0, mn1);
    zr32[96 + t]  = packbf(mx0, mx1);
    zr32[144 + t] = packbf(sd0, sd1);
    zr[64 + t]        = f2bf(m2);
    zr[96 + 64 + t]   = f2bf(mn2);
    zr[192 + 64 + t]  = f2bf(mx2);
    zr[288 + 64 + t]  = f2bf(sd2);
  } else {
    const unsigned* xg32 = (const unsigned*)(xpb + (size_t)g*DD);
    zr32[192 + t] = (d>0) ? xg32[t] : 0u;            // xp ch 0..63
    if(t < 8)  zr32[224 + t] = (d>0) ? xg32[32 + t] : 0u;  // xp ch 64..79
    if(t >= 8 && t < 16) zr32[232 + (t-8)] = (t==8) ? 0x3F80u : 0u; // const row + pad
  }
  if(lane == 0){
    float logd = logf(dc + 1.0f);
    sc[g] = make_float2(logd/AVG_LD, AVG_LD/logd);
  }
}

// build WcT [NOUT][KZ] bf16 from conv_w (layer slice)
__global__ void k_wprep(const float* __restrict__ cw, unsigned short* __restrict__ WcT){
  int idx = blockIdx.x*blockDim.x + threadIdx.x;
  if(idx >= NOUT*KZ) return;
  int j = idx / KZ;
  int r = idx % KZ;
  int ks = j / DD, c = j % DD;
  float val = 0.0f;
  if(r < 384){
    int stat = r/96, m = r%96;
    val = cw[(size_t)(ks*704 + stat*176 + 80 + m)*DD + c];
  } else if(r < 464){
    int m = r - 384;
    int b = ks*704 + m;
    val = cw[(size_t)b*DD + c] + cw[(size_t)(b+176)*DD + c] + cw[(size_t)(b+352)*DD + c];
  } else if(r == 464){
    float s = 0.0f; int b = ks*704 + 528;
    for(int m=0;m<80;++m) s += cw[(size_t)(b+m)*DD + c];
    val = S5 * s;
  }
  WcT[idx] = f2bf(val);
}

// LDS-free GEMM: fragments loaded directly from global (W is L2-resident, Z block-private)
__global__ __launch_bounds__(256) void k_gemm(
    const unsigned short* __restrict__ Z, const unsigned short* __restrict__ WcT,
    const float2* __restrict__ sc, const float* __restrict__ bias,
    float* __restrict__ outb, float* __restrict__ partial){
  __shared__ float sred[4][160];
  int tid = threadIdx.x;
  int wave = tid >> 6, lane = tid & 63;
  int r = lane & 15, q = lane >> 4;
  int m0 = blockIdx.x*128 + wave*32;
  const unsigned short* Ap = Z + (size_t)(m0 + r)*KZ + q*8;
  const unsigned short* Bp = WcT + (size_t)r*KZ + q*8;
  f32x4 acc0[15], acc1[15];
  #pragma unroll
  for(int i=0;i<15;++i){ acc0[i]=(f32x4){0.f,0.f,0.f,0.f}; acc1[i]=(f32x4){0.f,0.f,0.f,0.f}; }
  #pragma unroll 1
  for(int k0=0; k0<KZ; k0+=32){
    bf16x8 a0 = *(const bf16x8*)(Ap + k0);
    bf16x8 a1 = *(const bf16x8*)(Ap + 16*KZ + k0);
    #pragma unroll
    for(int ct=0; ct<15; ++ct){
      bf16x8 b = *(const bf16x8*)(Bp + (size_t)ct*16*KZ + k0);
      acc0[ct] = __builtin_amdgcn_mfma_f32_16x16x32_bf16(a0, b, acc0[ct], 0, 0, 0);
      acc1[ct] = __builtin_amdgcn_mfma_f32_16x16x32_bf16(a1, b, acc1[ct], 0, 0, 0);
    }
  }
  float colS[5], colQ[5];
  #pragma unroll
  for(int ct=0; ct<5; ++ct){ colS[ct]=0.f; colQ[ct]=0.f; }
  #pragma unroll
  for(int rr=0; rr<4; ++rr){
    int grow = m0 + q*4 + rr;
    if(grow < NN){
      float2 ab = sc[grow];
      #pragma unroll
      for(int ct=0; ct<5; ++ct){
        int c = ct*16 + r;
        float v = acc0[ct][rr] + ab.x*acc0[ct+5][rr] + ab.y*acc0[ct+10][rr] + bias[c];
        outb[(size_t)grow*DD + c] = v;
        colS[ct] += v; colQ[ct] += v*v;
      }
    }
  }
  #pragma unroll
  for(int rr=0; rr<4; ++rr){
    int grow = m0 + 16 + q*4 + rr;
    if(grow < NN){
      float2 ab = sc[grow];
      #pragma unroll
      for(int ct=0; ct<5; ++ct){
        int c = ct*16 + r;
        float v = acc1[ct][rr] + ab.x*acc1[ct+5][rr] + ab.y*acc1[ct+10][rr] + bias[c];
        outb[(size_t)grow*DD + c] = v;
        colS[ct] += v; colQ[ct] += v*v;
      }
    }
  }
  #pragma unroll
  for(int ct=0; ct<5; ++ct){
    colS[ct] += __shfl_xor(colS[ct], 16, 64);
    colS[ct] += __shfl_xor(colS[ct], 32, 64);
    colQ[ct] += __shfl_xor(colQ[ct], 16, 64);
    colQ[ct] += __shfl_xor(colQ[ct], 32, 64);
  }
  if(q == 0){
    #pragma unroll
    for(int ct=0; ct<5; ++ct){
      int c = ct*16 + r;
      sred[wave][c] = colS[ct];
      sred[wave][80+c] = colQ[ct];
    }
  }
  __syncthreads();
  if(tid < 160){
    partial[(size_t)blockIdx.x*160 + tid] =
      sred[0][tid] + sred[1][tid] + sred[2][tid] + sred[3][tid];
  }
}

__global__ void k_bnfin(const float* __restrict__ partial, float* __restrict__ murs){
  __shared__ float red[1024];
  __shared__ float tot[160];
  int tid = threadIdx.x;
  int c = tid % 160, stripe = tid / 160;
  float s = 0.0f;
  if(tid < 960){
    for(int b=stripe; b<NBLK; b+=6) s += partial[(size_t)b*160 + c];
  }
  red[tid] = s; __syncthreads();
  if(tid < 160){
    float t2 = 0.0f;
    for(int k=0;k<6;++k) t2 += red[k*160 + tid];
    tot[tid] = t2;
  }
  __syncthreads();
  if(tid < 80){
    float mu = tot[tid] / (float)NN;
    float var = tot[80+tid] / (float)NN - mu*mu;
    murs[tid] = mu;
    murs[80+tid] = rsqrtf(var + 1e-5f);
  }
}

// BN-apply + relu + residual, fused with next layer's xp computation
__global__ void k_apply(const float* __restrict__ outb, const float* __restrict__ murs,
                        const float* __restrict__ g_, const float* __restrict__ b_,
                        const float* __restrict__ xc, float* __restrict__ xn,
                        const float* __restrict__ PE, const float* __restrict__ pwn,
                        const float* __restrict__ pbn, unsigned short* __restrict__ xpb,
                        int do_xp){
  int idx = blockIdx.x*blockDim.x + threadIdx.x;
  if(idx >= NN*DD) return;
  int i = idx / DD, c = idx % DD;
  float v = (outb[idx] - murs[c]) * murs[DD+c] * g_[c] + b_[c];
  v = fmaxf(v, 0.0f);
  float xnew = v + xc[idx];
  xn[idx] = xnew;
  if(do_xp){
    float s = xnew + pbn[c];
    const float* per = PE + (size_t)i*PED;
    for(int p=0;p<PED;++p) s += per[p]*pwn[p*DD + c];
    xpb[idx] = f2bf(s);
  }
}

// ---------------- head ----------------
__device__ __forceinline__ int lbound(const int* b, int n, int v){
  int lo=0, hi=n;
  while(lo < hi){ int mid = (lo+hi)>>1; if(b[mid] < v) lo = mid+1; else hi = mid; }
  return lo;
}

__global__ void k_pool(const float* __restrict__ xf, const int* __restrict__ batch,
                       float* __restrict__ pooled){
  int g = blockIdx.x;
  int c = threadIdx.x;
  if(c >= DD) return;
  int lo = lbound(batch, NN, g), hi = lbound(batch, NN, g+1);
  float s = 0.0f;
  for(int i=lo;i<hi;++i) s += xf[(size_t)i*DD + c];
  int cnt = hi - lo;
  pooled[g*DD + c] = s / (float)(cnt > 0 ? cnt : 1);
}

__global__ void k_mlp(const float* __restrict__ pooled,
                      const float* __restrict__ w1, const float* __restrict__ b1,
                      const float* __restrict__ w2, const float* __restrict__ b2,
                      const float* __restrict__ w3, const float* __restrict__ b3,
                      float* __restrict__ out){
  __shared__ float W1[80*40], B1[40], W2[40*20], B2[20], W3[20];
  for(int i=threadIdx.x;i<80*40;i+=256) W1[i]=w1[i];
  for(int i=threadIdx.x;i<40;i+=256)    B1[i]=b1[i];
  for(int i=threadIdx.x;i<40*20;i+=256) W2[i]=w2[i];
  for(int i=threadIdx.x;i<20;i+=256)    B2[i]=b2[i];
  if(threadIdx.x<20) W3[threadIdx.x]=w3[threadIdx.x];
  __syncthreads();
  int g = threadIdx.x;
  float h1[40];
  #pragma unroll
  for(int j=0;j<40;++j) h1[j] = B1[j];
  for(int cc=0; cc<80; ++cc){
    float x = pooled[g*DD + cc];
    #pragma unroll
    for(int j=0;j<40;++j) h1[j] += x * W1[cc*40 + j];
  }
  #pragma unroll
  for(int j=0;j<40;++j) h1[j] = fmaxf(h1[j], 0.0f);
  float h2[20];
  #pragma unroll
  for(int j=0;j<20;++j) h2[j] = B2[j];
  for(int cc=0; cc<40; ++cc){
    float x = h1[cc];
    #pragma unroll
    for(int j=0;j<20;++j) h2[j] += x * W2[cc*20 + j];
  }
  float o = b3[0];
  #pragma unroll
  for(int j=0;j<20;++j) o += fmaxf(h2[j], 0.0f) * W3[j];
  out[g] = o;
}

// ---------------- launch ----------------
extern "C" void kernel_launch(void* const* d_in, const int* in_sizes, int n_in,
                              void* d_out, int out_size, void* d_ws, size_t ws_size,
                              hipStream_t stream){
  const float* x0     = (const float*)d_in[0];
  const int*   ei     = (const int*)d_in[1];
  const float* ea     = (const float*)d_in[2];
  const float* PE     = (const float*)d_in[3];
  const int*   batch  = (const int*)d_in[5];
  const float* pe_w   = (const float*)d_in[6];
  const float* pe_b   = (const float*)d_in[7];
  const float* conv_w = (const float*)d_in[8];
  const float* conv_b = (const float*)d_in[9];
  const float* bn_g   = (const float*)d_in[10];
  const float* bn_b   = (const float*)d_in[11];
  const float* w1 = (const float*)d_in[12];
  const float* b1 = (const float*)d_in[13];
  const float* w2 = (const float*)d_in[14];
  const float* b2 = (const float*)d_in[15];
  const float* w3 = (const float*)d_in[16];
  const float* b3 = (const float*)d_in[17];
  float* dout = (float*)d_out;

  char* p = (char*)d_ws;
  auto alloc = [&](size_t bytes)->char*{
    char* r = p; p += (bytes + 255) & ~(size_t)255; return r;
  };
  int* deg  = (int*)alloc((size_t)NN*4);
  int* pos  = (int*)alloc((size_t)NN*4);
  int* off  = (int*)alloc((size_t)(NN+1)*4);
  int* bsum = (int*)alloc((size_t)NB*4);
  int* bbase= (int*)alloc((size_t)NB*4);
  int* esrc = (int*)alloc((size_t)NE*4);
  unsigned short* ea_b = (unsigned short*)alloc((size_t)NE*EDIM*2);
  unsigned short* xpb  = (unsigned short*)alloc((size_t)NN*DD*2);
  unsigned short* Z    = (unsigned short*)alloc((size_t)MPAD*KZ*2);
  unsigned short* WcT[NLAY];
  for(int l=0;l<NLAY;++l) WcT[l] = (unsigned short*)alloc((size_t)NOUT*KZ*2);
  float* outb = (float*)alloc((size_t)NN*DD*4);
  float* xA   = (float*)alloc((size_t)NN*DD*4);
  float* xB   = (float*)alloc((size_t)NN*DD*4);
  float2* sc  = (float2*)alloc((size_t)MPAD*8);
  float* partial = (float*)alloc((size_t)NBLK*160*4);
  float* murs  = (float*)alloc(160*4);
  float* pooled = (float*)alloc((size_t)NG*DD*4);

  k_setup<<<(NN + (MPAD-NN)*KZ + 255)/256, 256, 0, stream>>>(deg, Z);
  k_hist<<<(NE+255)/256, 256, 0, stream>>>(ei + NE, deg);
  k_scan1<<<NB, 256, 0, stream>>>(deg, bsum);
  k_scan2<<<1, 256, 0, stream>>>(bsum, bbase, off);
  k_scan3<<<NB, 256, 0, stream>>>(deg, bbase, off, pos);
  k_fill<<<(NE+255)/256, 256, 0, stream>>>(ei, ea, pos, esrc, ea_b);
  for(int l=0;l<NLAY;++l)
    k_wprep<<<(NOUT*KZ+255)/256, 256, 0, stream>>>(conv_w + (size_t)l*2112*DD, WcT[l]);
  k_xp<<<(NN*DD+255)/256, 256, 0, stream>>>(x0, PE, pe_w, pe_b, xpb);

  const float* xc = x0;
  float* bufs[2] = {xA, xB};
  for(int l=0; l<NLAY; ++l){
    float* xn = bufs[l & 1];
    k_agg<<<(NN+3)/4, 256, 0, stream>>>(xpb, ea_b, off, esrc, Z, sc);
    k_gemm<<<NBLK, 256, 0, stream>>>(Z, WcT[l], sc, conv_b + l*DD, outb, partial);
    k_bnfin<<<1, 1024, 0, stream>>>(partial, murs);
    int do_xp = (l < NLAY-1) ? 1 : 0;
    k_apply<<<(NN*DD+255)/256, 256, 0, stream>>>(outb, murs, bn_g + l*DD, bn_b + l*DD,
                                                 xc, xn, PE,
                                                 pe_w + (size_t)(l+1 < NLAY ? l+1 : 0)*PED*DD,
                                                 pe_b + (l+1 < NLAY ? l+1 : 0)*DD,
                                                 xpb, do_xp);
    xc = xn;
  }
  k_pool<<<NG, 128, 0, stream>>>(xc, batch, pooled);
  k_mlp<<<1, 256, 0, stream>>>(pooled, w1, b1, w2, b2, w3, b3, dout);
}

// Round 5
// 772.858 us; speedup vs baseline: 1.7451x; 1.0577x over previous
//
#include <hip/hip_runtime.h>
#include <stdint.h>

#define NN 50000
#define DD 80
#define NE 800000
#define EDIM 16
#define PED 37
#define NG 256
#define NLAY 4
#define KZ 480
#define NOUT 240
#define MPAD 50048
#define NBLK (MPAD/128)
#define NB 196
#define AVG_LD 1.4059212841460147f
#define S5 0.0031622776601683794f

typedef __bf16 bf16x8 __attribute__((ext_vector_type(8)));
typedef float f32x4 __attribute__((ext_vector_type(4)));

__device__ __forceinline__ unsigned short f2bf(float f){
  union { float f; unsigned u; } v; v.f = f;
  return (unsigned short)((v.u + 0x7fffu + ((v.u >> 16) & 1u)) >> 16);
}
__device__ __forceinline__ float bf2f(unsigned short u){
  union { unsigned u; float f; } v; v.u = ((unsigned)u) << 16; return v.f;
}
__device__ __forceinline__ unsigned packbf(float a, float b){
  return (unsigned)f2bf(a) | ((unsigned)f2bf(b) << 16);
}

// ---------------- setup ----------------
__global__ void k_setup(int* deg, unsigned short* Z){
  int idx = blockIdx.x*blockDim.x + threadIdx.x;
  if(idx < NN) deg[idx] = 0;
  int t = idx - NN;
  if(t >= 0 && t < (MPAD-NN)*KZ) Z[(size_t)NN*KZ + t] = 0;
}

__global__ void k_hist(const int* __restrict__ tgt, int* deg){
  int e = blockIdx.x*blockDim.x + threadIdx.x;
  if(e < NE) atomicAdd(&deg[tgt[e]], 1);
}

__global__ void k_scan1(const int* __restrict__ deg, int* bsum){
  __shared__ int red[256];
  int i = blockIdx.x*256 + threadIdx.x;
  int v = (i < NN) ? deg[i] : 0;
  red[threadIdx.x] = v; __syncthreads();
  for(int d=128; d>0; d>>=1){
    if(threadIdx.x < d) red[threadIdx.x] += red[threadIdx.x + d];
    __syncthreads();
  }
  if(threadIdx.x == 0) bsum[blockIdx.x] = red[0];
}

__global__ void k_scan2(const int* __restrict__ bsum, int* bbase, int* off){
  __shared__ int s[256];
  int t = threadIdx.x;
  int v = (t < NB) ? bsum[t] : 0;
  s[t] = v; __syncthreads();
  for(int d=1; d<256; d<<=1){
    int u = (t >= d) ? s[t-d] : 0;
    __syncthreads();
    s[t] += u;
    __syncthreads();
  }
  if(t < NB) bbase[t] = s[t] - v;
  if(t == NB-1) off[NN] = s[t];
}

__global__ void k_scan3(const int* __restrict__ deg, const int* __restrict__ bbase,
                        int* off, int* pos){
  __shared__ int s[256];
  int t = threadIdx.x;
  int i = blockIdx.x*256 + t;
  int v = (i < NN) ? deg[i] : 0;
  s[t] = v; __syncthreads();
  for(int d=1; d<256; d<<=1){
    int u = (t >= d) ? s[t-d] : 0;
    __syncthreads();
    s[t] += u;
    __syncthreads();
  }
  int excl = s[t] - v + bbase[blockIdx.x];
  if(i < NN){ off[i] = excl; pos[i] = excl; }
}

// fill CSR: scatter src index AND edge_attr (bf16) in one pass
__global__ void k_fill(const int* __restrict__ ei, const float* __restrict__ ea,
                       int* pos, int* esrc, unsigned short* __restrict__ ea_b){
  int e = blockIdx.x*blockDim.x + threadIdx.x;
  if(e >= NE) return;
  int t = ei[NE + e];
  int idx = atomicAdd(&pos[t], 1);
  esrc[idx] = ei[e];
  const float4* s = (const float4*)(ea + (size_t)e*EDIM);
  float4 f0=s[0], f1=s[1], f2=s[2], f3=s[3];
  unsigned short tmp[16];
  tmp[0]=f2bf(f0.x); tmp[1]=f2bf(f0.y); tmp[2]=f2bf(f0.z); tmp[3]=f2bf(f0.w);
  tmp[4]=f2bf(f1.x); tmp[5]=f2bf(f1.y); tmp[6]=f2bf(f1.z); tmp[7]=f2bf(f1.w);
  tmp[8]=f2bf(f2.x); tmp[9]=f2bf(f2.y); tmp[10]=f2bf(f2.z); tmp[11]=f2bf(f2.w);
  tmp[12]=f2bf(f3.x); tmp[13]=f2bf(f3.y); tmp[14]=f2bf(f3.z); tmp[15]=f2bf(f3.w);
  uint4* d = (uint4*)(ea_b + (size_t)idx*EDIM);
  d[0] = *(uint4*)&tmp[0];
  d[1] = *(uint4*)&tmp[8];
}

// ---------------- per-layer ----------------
__global__ void k_xp(const float* __restrict__ xc, const float* __restrict__ PE,
                     const float* __restrict__ pw, const float* __restrict__ pb,
                     unsigned short* __restrict__ xpb){
  int idx = blockIdx.x*blockDim.x + threadIdx.x;
  if(idx >= NN*DD) return;
  int i = idx / DD, c = idx % DD;
  float s = xc[idx] + pb[c];
  const float* per = PE + (size_t)i*PED;
  for(int p=0;p<PED;++p) s += per[p]*pw[p*DD + c];
  xpb[idx] = f2bf(s);
}

// one 64-lane wave per node; halves process even/odd edges, combined by shfl_xor(32).
__global__ __launch_bounds__(256) void k_agg(
    const unsigned short* __restrict__ xpb, const unsigned short* __restrict__ ea_b,
    const int* __restrict__ off, const int* __restrict__ esrc,
    unsigned short* __restrict__ Z, float2* __restrict__ sc){
  int g = blockIdx.x*4 + (threadIdx.x >> 6);
  if(g >= NN) return;
  int lane = threadIdx.x & 63;
  int h = lane >> 5, t = lane & 31;
  int lo = off[g], hi = off[g+1];
  int d = hi - lo;
  float s0=0,s1=0,s2=0,q0=0,q1=0,q2=0;
  const float INF = __builtin_huge_valf();
  float mn0=INF,mn1=INF,mn2=INF,mx0=-INF,mx1=-INF,mx2=-INF;

  auto edge = [&](int j){
    int sr = esrc[j];
    const unsigned* xr32 = (const unsigned*)(xpb + (size_t)sr*DD);
    unsigned w = xr32[t];
    union {unsigned u; float f;} ua, ub;
    ua.u = w << 16; ub.u = w & 0xffff0000u;
    float v0 = ua.f, v1 = ub.f;
    unsigned short u2 = (t < 16) ? xpb[(size_t)sr*DD + 64 + t]
                                 : ea_b[(size_t)j*EDIM + (t - 16)];
    float v2 = bf2f(u2);
    s0+=v0; q0+=v0*v0; mn0=fminf(mn0,v0); mx0=fmaxf(mx0,v0);
    s1+=v1; q1+=v1*v1; mn1=fminf(mn1,v1); mx1=fmaxf(mx1,v1);
    s2+=v2; q2+=v2*v2; mn2=fminf(mn2,v2); mx2=fmaxf(mx2,v2);
  };
  int j = lo + h;
  for(; j + 2 < hi; j += 4){ edge(j); edge(j+2); }
  if(j < hi) edge(j);

  s0 += __shfl_xor(s0,32,64); s1 += __shfl_xor(s1,32,64); s2 += __shfl_xor(s2,32,64);
  q0 += __shfl_xor(q0,32,64); q1 += __shfl_xor(q1,32,64); q2 += __shfl_xor(q2,32,64);
  mn0 = fminf(mn0, __shfl_xor(mn0,32,64));
  mn1 = fminf(mn1, __shfl_xor(mn1,32,64));
  mn2 = fminf(mn2, __shfl_xor(mn2,32,64));
  mx0 = fmaxf(mx0, __shfl_xor(mx0,32,64));
  mx1 = fmaxf(mx1, __shfl_xor(mx1,32,64));
  mx2 = fmaxf(mx2, __shfl_xor(mx2,32,64));

  float dc = (float)(d>0?d:1);
  float inv = 1.0f/dc;
  float m0=s0*inv, m1=s1*inv, m2=s2*inv;
  float sd0 = sqrtf(fmaxf(q0*inv - m0*m0, 0.0f) + 1e-5f);
  float sd1 = sqrtf(fmaxf(q1*inv - m1*m1, 0.0f) + 1e-5f);
  float sd2 = sqrtf(fmaxf(q2*inv - m2*m2, 0.0f) + 1e-5f);
  if(d==0){ mn0=mn1=mn2=0.0f; mx0=mx1=mx2=0.0f; }

  unsigned* zr32 = (unsigned*)(Z + (size_t)g*KZ);
  unsigned short* zr = (unsigned short*)zr32;
  if(h == 0){
    zr32[t]       = packbf(m0, m1);
    zr32[48 + t]  = packbf(mn0, mn1);
    zr32[96 + t]  = packbf(mx0, mx1);
    zr32[144 + t] = packbf(sd0, sd1);
    zr[64 + t]        = f2bf(m2);
    zr[96 + 64 + t]   = f2bf(mn2);
    zr[192 + 64 + t]  = f2bf(mx2);
    zr[288 + 64 + t]  = f2bf(sd2);
  } else {
    const unsigned* xg32 = (const unsigned*)(xpb + (size_t)g*DD);
    zr32[192 + t] = (d>0) ? xg32[t] : 0u;            // xp ch 0..63
    if(t < 8)  zr32[224 + t] = (d>0) ? xg32[32 + t] : 0u;  // xp ch 64..79
    if(t >= 8 && t < 16) zr32[232 + (t-8)] = (t==8) ? 0x3F80u : 0u; // const row + pad
  }
  if(lane == 0){
    float logd = logf(dc + 1.0f);
    sc[g] = make_float2(logd/AVG_LD, AVG_LD/logd);
  }
}

// build WcT [NOUT][KZ] bf16 from conv_w (layer slice)
__global__ void k_wprep(const float* __restrict__ cw, unsigned short* __restrict__ WcT){
  int idx = blockIdx.x*blockDim.x + threadIdx.x;
  if(idx >= NOUT*KZ) return;
  int j = idx / KZ;
  int r = idx % KZ;
  int ks = j / DD, c = j % DD;
  float val = 0.0f;
  if(r < 384){
    int stat = r/96, m = r%96;
    val = cw[(size_t)(ks*704 + stat*176 + 80 + m)*DD + c];
  } else if(r < 464){
    int m = r - 384;
    int b = ks*704 + m;
    val = cw[(size_t)b*DD + c] + cw[(size_t)(b+176)*DD + c] + cw[(size_t)(b+352)*DD + c];
  } else if(r == 464){
    float s = 0.0f; int b = ks*704 + 528;
    for(int m=0;m<80;++m) s += cw[(size_t)(b+m)*DD + c];
    val = S5 * s;
  }
  WcT[idx] = f2bf(val);
}

// LDS-free GEMM: fragments loaded directly from global (W is L2-resident, Z block-private)
__global__ __launch_bounds__(256) void k_gemm(
    const unsigned short* __restrict__ Z, const unsigned short* __restrict__ WcT,
    const float2* __restrict__ sc, const float* __restrict__ bias,
    float* __restrict__ outb, float* __restrict__ partial){
  __shared__ float sred[4][160];
  int tid = threadIdx.x;
  int wave = tid >> 6, lane = tid & 63;
  int r = lane & 15, q = lane >> 4;
  int m0 = blockIdx.x*128 + wave*32;
  const unsigned short* Ap = Z + (size_t)(m0 + r)*KZ + q*8;
  const unsigned short* Bp = WcT + (size_t)r*KZ + q*8;
  f32x4 acc0[15], acc1[15];
  #pragma unroll
  for(int i=0;i<15;++i){ acc0[i]=(f32x4){0.f,0.f,0.f,0.f}; acc1[i]=(f32x4){0.f,0.f,0.f,0.f}; }
  #pragma unroll 1
  for(int k0=0; k0<KZ; k0+=32){
    bf16x8 a0 = *(const bf16x8*)(Ap + k0);
    bf16x8 a1 = *(const bf16x8*)(Ap + 16*KZ + k0);
    #pragma unroll
    for(int ct=0; ct<15; ++ct){
      bf16x8 b = *(const bf16x8*)(Bp + (size_t)ct*16*KZ + k0);
      acc0[ct] = __builtin_amdgcn_mfma_f32_16x16x32_bf16(a0, b, acc0[ct], 0, 0, 0);
      acc1[ct] = __builtin_amdgcn_mfma_f32_16x16x32_bf16(a1, b, acc1[ct], 0, 0, 0);
    }
  }
  float colS[5], colQ[5];
  #pragma unroll
  for(int ct=0; ct<5; ++ct){ colS[ct]=0.f; colQ[ct]=0.f; }
  #pragma unroll
  for(int rr=0; rr<4; ++rr){
    int grow = m0 + q*4 + rr;
    if(grow < NN){
      float2 ab = sc[grow];
      #pragma unroll
      for(int ct=0; ct<5; ++ct){
        int c = ct*16 + r;
        float v = acc0[ct][rr] + ab.x*acc0[ct+5][rr] + ab.y*acc0[ct+10][rr] + bias[c];
        outb[(size_t)grow*DD + c] = v;
        colS[ct] += v; colQ[ct] += v*v;
      }
    }
  }
  #pragma unroll
  for(int rr=0; rr<4; ++rr){
    int grow = m0 + 16 + q*4 + rr;
    if(grow < NN){
      float2 ab = sc[grow];
      #pragma unroll
      for(int ct=0; ct<5; ++ct){
        int c = ct*16 + r;
        float v = acc1[ct][rr] + ab.x*acc1[ct+5][rr] + ab.y*acc1[ct+10][rr] + bias[c];
        outb[(size_t)grow*DD + c] = v;
        colS[ct] += v; colQ[ct] += v*v;
      }
    }
  }
  #pragma unroll
  for(int ct=0; ct<5; ++ct){
    colS[ct] += __shfl_xor(colS[ct], 16, 64);
    colS[ct] += __shfl_xor(colS[ct], 32, 64);
    colQ[ct] += __shfl_xor(colQ[ct], 16, 64);
    colQ[ct] += __shfl_xor(colQ[ct], 32, 64);
  }
  if(q == 0){
    #pragma unroll
    for(int ct=0; ct<5; ++ct){
      int c = ct*16 + r;
      sred[wave][c] = colS[ct];
      sred[wave][80+c] = colQ[ct];
    }
  }
  __syncthreads();
  if(tid < 160){
    partial[(size_t)blockIdx.x*160 + tid] =
      sred[0][tid] + sred[1][tid] + sred[2][tid] + sred[3][tid];
  }
}

__global__ void k_bnfin(const float* __restrict__ partial, float* __restrict__ murs){
  __shared__ float red[1024];
  __shared__ float tot[160];
  int tid = threadIdx.x;
  int c = tid % 160, stripe = tid / 160;
  float s = 0.0f;
  if(tid < 960){
    for(int b=stripe; b<NBLK; b+=6) s += partial[(size_t)b*160 + c];
  }
  red[tid] = s; __syncthreads();
  if(tid < 160){
    float t2 = 0.0f;
    for(int k=0;k<6;++k) t2 += red[k*160 + tid];
    tot[tid] = t2;
  }
  __syncthreads();
  if(tid < 80){
    float mu = tot[tid] / (float)NN;
    float var = tot[80+tid] / (float)NN - mu*mu;
    murs[tid] = mu;
    murs[80+tid] = rsqrtf(var + 1e-5f);
  }
}

// BN-apply + relu + residual, fused with next layer's xp computation
__global__ void k_apply(const float* __restrict__ outb, const float* __restrict__ murs,
                        const float* __restrict__ g_, const float* __restrict__ b_,
                        const float* __restrict__ xc, float* __restrict__ xn,
                        const float* __restrict__ PE, const float* __restrict__ pwn,
                        const float* __restrict__ pbn, unsigned short* __restrict__ xpb,
                        int do_xp){
  int idx = blockIdx.x*blockDim.x + threadIdx.x;
  if(idx >= NN*DD) return;
  int i = idx / DD, c = idx % DD;
  float v = (outb[idx] - murs[c]) * murs[DD+c] * g_[c] + b_[c];
  v = fmaxf(v, 0.0f);
  float xnew = v + xc[idx];
  xn[idx] = xnew;
  if(do_xp){
    float s = xnew + pbn[c];
    const float* per = PE + (size_t)i*PED;
    for(int p=0;p<PED;++p) s += per[p]*pwn[p*DD + c];
    xpb[idx] = f2bf(s);
  }
}

// ---------------- head ----------------
__device__ __forceinline__ int lbound(const int* b, int n, int v){
  int lo=0, hi=n;
  while(lo < hi){ int mid = (lo+hi)>>1; if(b[mid] < v) lo = mid+1; else hi = mid; }
  return lo;
}

// one graph per block, 640 threads = 8 stripes x 80 channels, LDS reduce
__global__ __launch_bounds__(640) void k_pool(const float* __restrict__ xf,
                                              const int* __restrict__ batch,
                                              float* __restrict__ pooled){
  __shared__ float red[8][80];
  int g = blockIdx.x;
  int tid = threadIdx.x;
  int stripe = tid / 80, c = tid % 80;
  int lo = lbound(batch, NN, g), hi = lbound(batch, NN, g+1);
  float s = 0.0f;
  for(int i = lo + stripe; i < hi; i += 8) s += xf[(size_t)i*DD + c];
  red[stripe][c] = s;
  __syncthreads();
  if(tid < 80){
    float tsum = 0.0f;
    #pragma unroll
    for(int k=0;k<8;++k) tsum += red[k][tid];
    int cnt = hi - lo;
    pooled[g*DD + tid] = tsum / (float)(cnt > 0 ? cnt : 1);
  }
}

__global__ void k_mlp(const float* __restrict__ pooled,
                      const float* __restrict__ w1, const float* __restrict__ b1,
                      const float* __restrict__ w2, const float* __restrict__ b2,
                      const float* __restrict__ w3, const float* __restrict__ b3,
                      float* __restrict__ out){
  __shared__ float W1[80*40], B1[40], W2[40*20], B2[20], W3[20];
  for(int i=threadIdx.x;i<80*40;i+=256) W1[i]=w1[i];
  for(int i=threadIdx.x;i<40;i+=256)    B1[i]=b1[i];
  for(int i=threadIdx.x;i<40*20;i+=256) W2[i]=w2[i];
  for(int i=threadIdx.x;i<20;i+=256)    B2[i]=b2[i];
  if(threadIdx.x<20) W3[threadIdx.x]=w3[threadIdx.x];
  __syncthreads();
  int g = threadIdx.x;
  float h1[40];
  #pragma unroll
  for(int j=0;j<40;++j) h1[j] = B1[j];
  for(int cc=0; cc<80; ++cc){
    float x = pooled[g*DD + cc];
    #pragma unroll
    for(int j=0;j<40;++j) h1[j] += x * W1[cc*40 + j];
  }
  #pragma unroll
  for(int j=0;j<40;++j) h1[j] = fmaxf(h1[j], 0.0f);
  float h2[20];
  #pragma unroll
  for(int j=0;j<20;++j) h2[j] = B2[j];
  for(int cc=0; cc<40; ++cc){
    float x = h1[cc];
    #pragma unroll
    for(int j=0;j<20;++j) h2[j] += x * W2[cc*20 + j];
  }
  float o = b3[0];
  #pragma unroll
  for(int j=0;j<20;++j) o += fmaxf(h2[j], 0.0f) * W3[j];
  out[g] = o;
}

// ---------------- launch ----------------
extern "C" void kernel_launch(void* const* d_in, const int* in_sizes, int n_in,
                              void* d_out, int out_size, void* d_ws, size_t ws_size,
                              hipStream_t stream){
  const float* x0     = (const float*)d_in[0];
  const int*   ei     = (const int*)d_in[1];
  const float* ea     = (const float*)d_in[2];
  const float* PE     = (const float*)d_in[3];
  const int*   batch  = (const int*)d_in[5];
  const float* pe_w   = (const float*)d_in[6];
  const float* pe_b   = (const float*)d_in[7];
  const float* conv_w = (const float*)d_in[8];
  const float* conv_b = (const float*)d_in[9];
  const float* bn_g   = (const float*)d_in[10];
  const float* bn_b   = (const float*)d_in[11];
  const float* w1 = (const float*)d_in[12];
  const float* b1 = (const float*)d_in[13];
  const float* w2 = (const float*)d_in[14];
  const float* b2 = (const float*)d_in[15];
  const float* w3 = (const float*)d_in[16];
  const float* b3 = (const float*)d_in[17];
  float* dout = (float*)d_out;

  char* p = (char*)d_ws;
  auto alloc = [&](size_t bytes)->char*{
    char* r = p; p += (bytes + 255) & ~(size_t)255; return r;
  };
  int* deg  = (int*)alloc((size_t)NN*4);
  int* pos  = (int*)alloc((size_t)NN*4);
  int* off  = (int*)alloc((size_t)(NN+1)*4);
  int* bsum = (int*)alloc((size_t)NB*4);
  int* bbase= (int*)alloc((size_t)NB*4);
  int* esrc = (int*)alloc((size_t)NE*4);
  unsigned short* ea_b = (unsigned short*)alloc((size_t)NE*EDIM*2);
  unsigned short* xpb  = (unsigned short*)alloc((size_t)NN*DD*2);
  unsigned short* Z    = (unsigned short*)alloc((size_t)MPAD*KZ*2);
  unsigned short* WcT[NLAY];
  for(int l=0;l<NLAY;++l) WcT[l] = (unsigned short*)alloc((size_t)NOUT*KZ*2);
  float* outb = (float*)alloc((size_t)NN*DD*4);
  float* xA   = (float*)alloc((size_t)NN*DD*4);
  float* xB   = (float*)alloc((size_t)NN*DD*4);
  float2* sc  = (float2*)alloc((size_t)MPAD*8);
  float* partial = (float*)alloc((size_t)NBLK*160*4);
  float* murs  = (float*)alloc(160*4);
  float* pooled = (float*)alloc((size_t)NG*DD*4);

  k_setup<<<(NN + (MPAD-NN)*KZ + 255)/256, 256, 0, stream>>>(deg, Z);
  k_hist<<<(NE+255)/256, 256, 0, stream>>>(ei + NE, deg);
  k_scan1<<<NB, 256, 0, stream>>>(deg, bsum);
  k_scan2<<<1, 256, 0, stream>>>(bsum, bbase, off);
  k_scan3<<<NB, 256, 0, stream>>>(deg, bbase, off, pos);
  k_fill<<<(NE+255)/256, 256, 0, stream>>>(ei, ea, pos, esrc, ea_b);
  for(int l=0;l<NLAY;++l)
    k_wprep<<<(NOUT*KZ+255)/256, 256, 0, stream>>>(conv_w + (size_t)l*2112*DD, WcT[l]);
  k_xp<<<(NN*DD+255)/256, 256, 0, stream>>>(x0, PE, pe_w, pe_b, xpb);

  const float* xc = x0;
  float* bufs[2] = {xA, xB};
  for(int l=0; l<NLAY; ++l){
    float* xn = bufs[l & 1];
    k_agg<<<(NN+3)/4, 256, 0, stream>>>(xpb, ea_b, off, esrc, Z, sc);
    k_gemm<<<NBLK, 256, 0, stream>>>(Z, WcT[l], sc, conv_b + l*DD, outb, partial);
    k_bnfin<<<1, 1024, 0, stream>>>(partial, murs);
    int do_xp = (l < NLAY-1) ? 1 : 0;
    k_apply<<<(NN*DD+255)/256, 256, 0, stream>>>(outb, murs, bn_g + l*DD, bn_b + l*DD,
                                                 xc, xn, PE,
                                                 pe_w + (size_t)(l+1 < NLAY ? l+1 : 0)*PED*DD,
                                                 pe_b + (l+1 < NLAY ? l+1 : 0)*DD,
                                                 xpb, do_xp);
    xc = xn;
  }
  k_pool<<<NG, 640, 0, stream>>>(xc, batch, pooled);
  k_mlp<<<1, 256, 0, stream>>>(pooled, w1, b1, w2, b2, w3, b3, dout);
}